// Round 9
// baseline (648.653 us; speedup 1.0000x reference)
//
#include <hip/hip_runtime.h>
#include <hip/hip_bf16.h>
#include <math.h>

typedef unsigned short u16;
typedef __attribute__((ext_vector_type(8))) short bf16x8;
typedef __attribute__((ext_vector_type(4))) float f32x4;
typedef __attribute__((ext_vector_type(4))) unsigned u32x4;
typedef __attribute__((ext_vector_type(2))) unsigned u32x2;

#define N_NODES 100000
#define IN_CH 128
#define HID 256
#define EMB 128
#define N_PAIRS 500000
#define BN_EPS 1e-5f

#define TA 32   // nodes per block (kernel A)
#define PBM 64  // pairs per block (kernel B)

// ---- bf16 helpers ----
__device__ __forceinline__ u16 f2bf(float f) {            // scalar RNE (prep kernel)
    unsigned u = __builtin_bit_cast(unsigned, f);
    unsigned r = u + 0x7FFFu + ((u >> 16) & 1u);
    return (u16)(r >> 16);
}
__device__ __forceinline__ float bf2f(u16 h) {
    unsigned u = ((unsigned)h) << 16;
    return __builtin_bit_cast(float, u);
}
// packed pair conversion -> v_cvt_pk_bf16_f32
__device__ __forceinline__ unsigned pk2(float a, float b) {
    __hip_bfloat162 h = __float22bfloat162_rn(make_float2(a, b));
    unsigned u;
    __builtin_memcpy(&u, &h, sizeof(u));
    return u;
}
__device__ __forceinline__ float lo16f(unsigned u) { return __builtin_bit_cast(float, u << 16); }
__device__ __forceinline__ float hi16f(unsigned u) { return __builtin_bit_cast(float, u & 0xffff0000u); }

// ---------------------------------------------------------------------------
// Weight prep into MFMA A-operand fragment-linear layout (weights on M-side):
// idx = ((mt*KS + ks)*64 + l)*8 + j ; value = W[k][n], n = mt*16 + (l&15),
// k = ks*32 + (l>>4)*8 + j.
// ---------------------------------------------------------------------------
__global__ __launch_bounds__(256) void prep_weights(
    const float* __restrict__ SW1, const float* __restrict__ SW2,
    u16* __restrict__ w1h, u16* __restrict__ w1l,
    u16* __restrict__ w2h, u16* __restrict__ w2l)
{
    const int tid = blockIdx.x * 256 + threadIdx.x;
    if (tid < 131072) {                       // W1^T frags: 16 mt x 16 ks
        const int j = tid & 7, l = (tid >> 3) & 63, ks = (tid >> 9) & 15, mt = tid >> 13;
        const int n = mt * 16 + (l & 15);
        const int k = ks * 32 + ((l >> 4) << 3) + j;
        const float v = SW1[(size_t)k * HID + n];
        const u16 h = f2bf(v);
        w1h[tid] = h;
        w1l[tid] = f2bf(v - bf2f(h));
    } else if (tid < 131072 + 32768) {        // W2^T frags: 8 mt x 8 ks
        const int t2 = tid - 131072;
        const int j = t2 & 7, l = (t2 >> 3) & 63, ks = (t2 >> 9) & 7, mt = t2 >> 12;
        const int n = mt * 16 + (l & 15);
        const int k = ks * 32 + ((l >> 4) << 3) + j;
        const float v = SW2[(size_t)k * (HID / 2) + n];
        const u16 h = f2bf(v);
        w2h[t2] = h;
        w2l[t2] = f2bf(v - bf2f(h));
    }
}

// ---------------------------------------------------------------------------
// Kernel A: z = relu( relu(BN(clip((x-mean)/std) @ W1 + b1)) @ W2 + b2 )
// (unchanged — fp32 register-tiled)
// ---------------------------------------------------------------------------
__global__ __launch_bounds__(256) void node_mlp_kernel(
    const float* __restrict__ x,
    const float* __restrict__ x_mean,
    const float* __restrict__ x_std,
    const float* __restrict__ W1,
    const float* __restrict__ b1,
    const float* __restrict__ bn_gamma,
    const float* __restrict__ bn_beta,
    const float* __restrict__ bn_mean,
    const float* __restrict__ bn_var,
    const float* __restrict__ W2,
    const float* __restrict__ b2,
    float* __restrict__ z)
{
    __shared__ __align__(16) float xfT[IN_CH][36];
    __shared__ __align__(16) float hT[HID][36];

    const int t  = threadIdx.x;
    const int n0 = blockIdx.x * TA;

    for (int f = t; f < TA * (IN_CH / 4); f += 256) {
        const int n  = f >> 5;
        const int cg = f & 31;
        float4 v = *reinterpret_cast<const float4*>(x + (size_t)(n0 + n) * IN_CH + cg * 4);
        float vv[4] = {v.x, v.y, v.z, v.w};
        #pragma unroll
        for (int e = 0; e < 4; ++e) {
            const int c = cg * 4 + e;
            float val = vv[e];
            if (!isfinite(val)) val = 0.0f;
            val = (val - x_mean[c]) / x_std[c];
            val = fminf(fmaxf(val, -10.0f), 10.0f);
            xfT[c][n] = val;
        }
    }
    __syncthreads();

    const int i0 = t >> 6;
    const int j  = t & 63;

    {
        float acc[8][4];
        #pragma unroll
        for (int r = 0; r < 8; ++r)
            #pragma unroll
            for (int c = 0; c < 4; ++c) acc[r][c] = 0.0f;

        #pragma unroll 4
        for (int k = 0; k < IN_CH; ++k) {
            float a[8];
            *reinterpret_cast<float4*>(&a[0]) = *reinterpret_cast<const float4*>(&xfT[k][i0 * 8]);
            *reinterpret_cast<float4*>(&a[4]) = *reinterpret_cast<const float4*>(&xfT[k][i0 * 8 + 4]);
            float w[4];
            *reinterpret_cast<float4*>(w) = *reinterpret_cast<const float4*>(W1 + (size_t)k * HID + j * 4);
            #pragma unroll
            for (int r = 0; r < 8; ++r)
                #pragma unroll
                for (int c = 0; c < 4; ++c)
                    acc[r][c] = fmaf(a[r], w[c], acc[r][c]);
        }

        float b1v[4], gv[4], bev[4], mv[4], vv[4];
        *reinterpret_cast<float4*>(b1v) = *reinterpret_cast<const float4*>(b1 + j * 4);
        *reinterpret_cast<float4*>(gv)  = *reinterpret_cast<const float4*>(bn_gamma + j * 4);
        *reinterpret_cast<float4*>(bev) = *reinterpret_cast<const float4*>(bn_beta + j * 4);
        *reinterpret_cast<float4*>(mv)  = *reinterpret_cast<const float4*>(bn_mean + j * 4);
        *reinterpret_cast<float4*>(vv)  = *reinterpret_cast<const float4*>(bn_var + j * 4);

        #pragma unroll
        for (int c = 0; c < 4; ++c) {
            const float scale = gv[c] * rsqrtf(vv[c] + BN_EPS);
            float tmp[8];
            #pragma unroll
            for (int r = 0; r < 8; ++r) {
                const float hv = (acc[r][c] + b1v[c] - mv[c]) * scale + bev[c];
                tmp[r] = fmaxf(hv, 0.0f);
            }
            *reinterpret_cast<float4*>(&hT[j * 4 + c][i0 * 8])     = *reinterpret_cast<float4*>(&tmp[0]);
            *reinterpret_cast<float4*>(&hT[j * 4 + c][i0 * 8 + 4]) = *reinterpret_cast<float4*>(&tmp[4]);
        }
    }
    __syncthreads();

    {
        float acc[8][2];
        #pragma unroll
        for (int r = 0; r < 8; ++r) { acc[r][0] = 0.0f; acc[r][1] = 0.0f; }

        #pragma unroll 4
        for (int k = 0; k < HID; ++k) {
            float a[8];
            *reinterpret_cast<float4*>(&a[0]) = *reinterpret_cast<const float4*>(&hT[k][i0 * 8]);
            *reinterpret_cast<float4*>(&a[4]) = *reinterpret_cast<const float4*>(&hT[k][i0 * 8 + 4]);
            const float2 w = *reinterpret_cast<const float2*>(W2 + (size_t)k * EMB + j * 2);
            #pragma unroll
            for (int r = 0; r < 8; ++r) {
                acc[r][0] = fmaf(a[r], w.x, acc[r][0]);
                acc[r][1] = fmaf(a[r], w.y, acc[r][1]);
            }
        }
        const float2 b2v = *reinterpret_cast<const float2*>(b2 + j * 2);
        #pragma unroll
        for (int r = 0; r < 8; ++r) {
            float2 o;
            o.x = fmaxf(acc[r][0] + b2v.x, 0.0f);
            o.y = fmaxf(acc[r][1] + b2v.y, 0.0f);
            *reinterpret_cast<float2*>(z + (size_t)(n0 + i0 * 8 + r) * EMB + j * 2) = o;
        }
    }
}

// ---------------------------------------------------------------------------
// Kernel B (MFMA): 64 pairs/block, 8 waves (512 thr), 32 KB segmented LDS.
// Register-budget design: L1 acc[2][4] (32 AGPR, wave owns mt {2w,2w+1}),
// L2 acc2[4] (16 AGPR, wave owns mt2 = w) => 48 AGPR; arch VGPR target <= 80
// so total <= 128 -> 4 waves/SIMD (16 waves/CU), double rounds 4-8's 2/SIMD.
// K=512 via four 128-K segments through one 32 KB buffer (round-8 scheme):
//   seg0 [s|d] ch0:64 (ks 0,1,4,5) -> seg2 [p|ad] ch0:64 (ks 8,9,12,13)
//   seg1 [s|d] ch64:128 (ks 2,3,6,7) -> seg3 [p|ad] ch64:128 (ks 10,11,14,15)
// L2: 2 rounds; round g: waves with (w&1)==g stage chunk c=w at slot w>>1.
// NOTE: no 2nd __launch_bounds__ arg ((512,4) => 64-reg spill r6; (512,2) =>
// 1-block residency r7).
// ---------------------------------------------------------------------------
__global__ __launch_bounds__(512) void pair_mfma_kernel(
    const float* __restrict__ z,
    const int* __restrict__ pairs,
    const float* __restrict__ logdeg,
    const u16* __restrict__ w1h, const u16* __restrict__ w1l,
    const u16* __restrict__ w2h, const u16* __restrict__ w2l,
    const float* __restrict__ SW1, const float* __restrict__ Sb1,
    const float* __restrict__ Sb2,
    const float* __restrict__ SW3, const float* __restrict__ Sb3,
    float* __restrict__ out)
{
    __shared__ __align__(16) u16 F[2 * 8192];    // 32 KB: [half][slot 0..3][nt 0..3][512]
    __shared__ float red[8][4][16];              // 2 KB

    const int t   = threadIdx.x;
    const int w   = t >> 6;        // wave 0..7
    const int l   = t & 63;
    const int l15 = l & 15;
    const int l4  = l >> 4;
    const int p0  = blockIdx.x * PBM;

    // split 8 floats and store hi/lo u32x4 at u16-index base
    #define SPLIT_STORE8(vals, base) { \
        u32x4 hv, lv; \
        _Pragma("unroll") \
        for (int q = 0; q < 4; ++q) { \
            const float a = (vals)[2 * q]; \
            const float b = (vals)[2 * q + 1]; \
            const unsigned hw = pk2(a, b); \
            hv[q] = hw; \
            lv[q] = pk2(a - lo16f(hw), b - hi16f(hw)); \
        } \
        *reinterpret_cast<u32x4*>(&F[(base)])        = hv; \
        *reinterpret_cast<u32x4*>(&F[8192 + (base)]) = lv; }

    // thread (w,l): pair l, channels [w*8, w*8+8) of the current 64-ch half
    // s-type -> slot w>>2 ; d-type -> slot 2+(w>>2) ; q = w&3
    const int baseS = (((w >> 2)) * 4 + (l >> 4)) * 512 + (l15 + 16 * (w & 3)) * 8;
    const int baseD = ((2 + (w >> 2)) * 4 + (l >> 4)) * 512 + (l15 + 16 * (w & 3)) * 8;

    const int gp  = (p0 + l < N_PAIRS) ? (p0 + l) : (N_PAIRS - 1);
    const int gsi = pairs[(size_t)gp * 2 + 0];
    const int gdi = pairs[(size_t)gp * 2 + 1];

    // ---- stage a [s|d] segment for channel-half h (0 or 1) ----
    auto stage_sd = [&](int h) {
        const float* zs = z + (size_t)gsi * EMB + h * 64 + w * 8;
        const float* zd = z + (size_t)gdi * EMB + h * 64 + w * 8;
        float sv[8], dv[8];
        *reinterpret_cast<float4*>(&sv[0]) = *reinterpret_cast<const float4*>(zs);
        *reinterpret_cast<float4*>(&sv[4]) = *reinterpret_cast<const float4*>(zs + 4);
        *reinterpret_cast<float4*>(&dv[0]) = *reinterpret_cast<const float4*>(zd);
        *reinterpret_cast<float4*>(&dv[4]) = *reinterpret_cast<const float4*>(zd + 4);
        SPLIT_STORE8(sv, baseS);
        SPLIT_STORE8(dv, baseD);
    };

    // ---- prefetch epilogue-1 gather data ----
    float ldS[4], ldD[4];
    #pragma unroll
    for (int nt = 0; nt < 4; ++nt) {
        const int pidx = (p0 + nt * 16 + l15 < N_PAIRS) ? (p0 + nt * 16 + l15) : (N_PAIRS - 1);
        ldS[nt] = logdeg[pairs[(size_t)pidx * 2 + 0]];
        ldD[nt] = logdeg[pairs[(size_t)pidx * 2 + 1]];
    }

    stage_sd(0);
    __syncthreads();

    // ---- layer 1 accumulators: wave w owns mt {2w, 2w+1} ----
    f32x4 acc[2][4];
    #pragma unroll
    for (int m = 0; m < 2; ++m)
        #pragma unroll
        for (int nt = 0; nt < 4; ++nt) acc[m][nt] = (f32x4){0.f, 0.f, 0.f, 0.f};

    // one 128-K segment: slots 0..3 use weight ks {k0,k1,k2,k3}
    auto run_pass = [&](int k0, int k1, int k2, int k3) {
        const int ksg[4] = {k0, k1, k2, k3};
        #pragma unroll
        for (int sl = 0; sl < 4; ++sl) {
            bf16x8 wh[2], wl[2];
            #pragma unroll
            for (int m = 0; m < 2; ++m) {
                const size_t bo = ((size_t)((w * 2 + m) * 16 + ksg[sl]) * 64 + l) * 8;
                wh[m] = *reinterpret_cast<const bf16x8*>(&w1h[bo]);
                wl[m] = *reinterpret_cast<const bf16x8*>(&w1l[bo]);
            }
            // nt processed in pairs: <=16 feature regs live
            #pragma unroll
            for (int nh = 0; nh < 2; ++nh) {
                bf16x8 fh[2], fl[2];
                #pragma unroll
                for (int e = 0; e < 2; ++e) {
                    const int fb = (sl * 4 + nh * 2 + e) * 512 + l * 8;
                    fh[e] = *reinterpret_cast<const bf16x8*>(&F[fb]);
                    fl[e] = *reinterpret_cast<const bf16x8*>(&F[8192 + fb]);
                }
                #pragma unroll
                for (int m = 0; m < 2; ++m)
                    #pragma unroll
                    for (int e = 0; e < 2; ++e)
                        acc[m][nh * 2 + e] = __builtin_amdgcn_mfma_f32_16x16x32_bf16(wh[m], fh[e], acc[m][nh * 2 + e], 0, 0, 0);
                #pragma unroll
                for (int m = 0; m < 2; ++m)
                    #pragma unroll
                    for (int e = 0; e < 2; ++e)
                        acc[m][nh * 2 + e] = __builtin_amdgcn_mfma_f32_16x16x32_bf16(wl[m], fh[e], acc[m][nh * 2 + e], 0, 0, 0);
                #pragma unroll
                for (int m = 0; m < 2; ++m)
                    #pragma unroll
                    for (int e = 0; e < 2; ++e)
                        acc[m][nh * 2 + e] = __builtin_amdgcn_mfma_f32_16x16x32_bf16(wh[m], fl[e], acc[m][nh * 2 + e], 0, 0, 0);
            }
        }
    };

    // transition: read own quantized s~,d~; p = s~*d~, ad = |s~-d~|
    auto rebuild = [&](float* pv, float* av) {
        u32x4 sh = *reinterpret_cast<const u32x4*>(&F[baseS]);
        u32x4 sl = *reinterpret_cast<const u32x4*>(&F[8192 + baseS]);
        u32x4 dh = *reinterpret_cast<const u32x4*>(&F[baseD]);
        u32x4 dl = *reinterpret_cast<const u32x4*>(&F[8192 + baseD]);
        #pragma unroll
        for (int qq = 0; qq < 4; ++qq) {
            const float s0 = lo16f(sh[qq]) + lo16f(sl[qq]);
            const float s1 = hi16f(sh[qq]) + hi16f(sl[qq]);
            const float d0 = lo16f(dh[qq]) + lo16f(dl[qq]);
            const float d1 = hi16f(dh[qq]) + hi16f(dl[qq]);
            pv[2 * qq]     = s0 * d0;
            pv[2 * qq + 1] = s1 * d1;
            av[2 * qq]     = fabsf(s0 - d0);
            av[2 * qq + 1] = fabsf(s1 - d1);
        }
    };

    // ---- seg0: [s|d] ch 0:64 ----
    run_pass(0, 1, 4, 5);
    {
        float pv[8], av[8];
        rebuild(pv, av);
        __syncthreads();              // everyone done reading seg0
        SPLIT_STORE8(pv, baseS);
        SPLIT_STORE8(av, baseD);
    }
    __syncthreads();

    // ---- seg2: [p|ad] ch 0:64 ----
    run_pass(8, 9, 12, 13);
    __syncthreads();

    // ---- seg1: [s|d] ch 64:128 ----
    stage_sd(1);
    __syncthreads();

    run_pass(2, 3, 6, 7);
    {
        float pv[8], av[8];
        rebuild(pv, av);
        __syncthreads();
        SPLIT_STORE8(pv, baseS);
        SPLIT_STORE8(av, baseD);
    }
    __syncthreads();

    // ---- seg3: [p|ad] ch 64:128 ----
    run_pass(10, 11, 14, 15);
    __syncthreads();                  // layer 1 done; F reusable

    // ---- layer 2: 2 rounds; round g: waves (w&1)==g stage chunk c=w -> slot w>>1 ----
    f32x4 acc2[4];
    #pragma unroll
    for (int nt = 0; nt < 4; ++nt) acc2[nt] = (f32x4){0.f, 0.f, 0.f, 0.f};

    #pragma unroll
    for (int g = 0; g < 2; ++g) {
        if ((w & 1) == g) {
            // epilogue-1: bias + logdeg rank-2 + relu; s1 frags for chunk w
            #pragma unroll
            for (int m = 0; m < 2; ++m) {
                const int mt = w * 2 + m;
                const int nb = mt * 16 + l4 * 4;
                float sb[4], wa[4], wb[4];
                *reinterpret_cast<float4*>(sb) = *reinterpret_cast<const float4*>(&Sb1[nb]);
                *reinterpret_cast<float4*>(wa) = *reinterpret_cast<const float4*>(&SW1[(size_t)512 * HID + nb]);
                *reinterpret_cast<float4*>(wb) = *reinterpret_cast<const float4*>(&SW1[(size_t)513 * HID + nb]);
                #pragma unroll
                for (int nt = 0; nt < 4; ++nt) {
                    float v[4];
                    #pragma unroll
                    for (int r = 0; r < 4; ++r) {
                        float x0 = acc[m][nt][r] + sb[r];
                        x0 = fmaf(ldS[nt], wa[r], x0);
                        x0 = fmaf(ldD[nt], wb[r], x0);
                        v[r] = fmaxf(x0, 0.0f);
                    }
                    const unsigned h0 = pk2(v[0], v[1]);
                    const unsigned h1 = pk2(v[2], v[3]);
                    u32x2 hv, lv;
                    hv[0] = h0; hv[1] = h1;
                    lv[0] = pk2(v[0] - lo16f(h0), v[1] - hi16f(h0));
                    lv[1] = pk2(v[2] - lo16f(h1), v[3] - hi16f(h1));
                    const int base = ((w >> 1) * 4 + nt) * 512
                                   + (l15 + 16 * (m * 2 + (l4 >> 1))) * 8
                                   + (l4 & 1) * 4;
                    *reinterpret_cast<u32x2*>(&F[base])        = hv;
                    *reinterpret_cast<u32x2*>(&F[8192 + base]) = lv;
                }
            }
        }
        __syncthreads();

        // MFMA: 4 chunk slots cs hold chunks c = 2cs+g -> ks2 = c ; mt2 = w
        #pragma unroll
        for (int cs = 0; cs < 4; ++cs) {
            const int ks2 = cs * 2 + g;
            const size_t bo = ((size_t)(w * 8 + ks2) * 64 + l) * 8;
            bf16x8 wh2 = *reinterpret_cast<const bf16x8*>(&w2h[bo]);
            bf16x8 wl2 = *reinterpret_cast<const bf16x8*>(&w2l[bo]);
            #pragma unroll
            for (int nh = 0; nh < 2; ++nh) {
                bf16x8 fh[2], fl[2];
                #pragma unroll
                for (int e = 0; e < 2; ++e) {
                    const int fb = (cs * 4 + nh * 2 + e) * 512 + l * 8;
                    fh[e] = *reinterpret_cast<const bf16x8*>(&F[fb]);
                    fl[e] = *reinterpret_cast<const bf16x8*>(&F[8192 + fb]);
                }
                #pragma unroll
                for (int e = 0; e < 2; ++e)
                    acc2[nh * 2 + e] = __builtin_amdgcn_mfma_f32_16x16x32_bf16(wh2, fh[e], acc2[nh * 2 + e], 0, 0, 0);
                #pragma unroll
                for (int e = 0; e < 2; ++e)
                    acc2[nh * 2 + e] = __builtin_amdgcn_mfma_f32_16x16x32_bf16(wl2, fh[e], acc2[nh * 2 + e], 0, 0, 0);
                #pragma unroll
                for (int e = 0; e < 2; ++e)
                    acc2[nh * 2 + e] = __builtin_amdgcn_mfma_f32_16x16x32_bf16(wh2, fl[e], acc2[nh * 2 + e], 0, 0, 0);
            }
        }
        __syncthreads();   // before round-1 staging overwrites
    }

    // ---- epilogue 2 + layer 3: wave w owns cols [w*16, w*16+16) ----
    {
        float part[4] = {0.f, 0.f, 0.f, 0.f};
        const int nb2 = w * 16 + l4 * 4;
        float sb[4], w3[4];
        *reinterpret_cast<float4*>(sb) = *reinterpret_cast<const float4*>(&Sb2[nb2]);
        *reinterpret_cast<float4*>(w3) = *reinterpret_cast<const float4*>(&SW3[nb2]);
        #pragma unroll
        for (int nt = 0; nt < 4; ++nt)
            #pragma unroll
            for (int r = 0; r < 4; ++r)
                part[nt] = fmaf(fmaxf(acc2[nt][r] + sb[r], 0.0f), w3[r], part[nt]);
        #pragma unroll
        for (int nt = 0; nt < 4; ++nt) {
            part[nt] += __shfl_xor(part[nt], 16);
            part[nt] += __shfl_xor(part[nt], 32);
        }
        if (l < 16) {
            #pragma unroll
            for (int nt = 0; nt < 4; ++nt) red[w][nt][l15] = part[nt];
        }
    }
    __syncthreads();

    if (t < 64) {
        const int nt = t >> 4, pp = t & 15;
        float v = Sb3[0];
        #pragma unroll
        for (int ww = 0; ww < 8; ++ww) v += red[ww][nt][pp];
        if (isnan(v)) v = 0.0f;
        else if (isinf(v)) v = (v > 0.0f) ? 20.0f : -20.0f;
        const int pidx = p0 + nt * 16 + pp;
        if (pidx < N_PAIRS) out[pidx] = v;
    }
    #undef SPLIT_STORE8
}

// ---------------------------------------------------------------------------
extern "C" void kernel_launch(void* const* d_in, const int* in_sizes, int n_in,
                              void* d_out, int out_size, void* d_ws, size_t ws_size,
                              hipStream_t stream)
{
    const float* x        = (const float*)d_in[0];
    // d_in[1] = edge_index : unused by the reference
    const int*   pairs    = (const int*)d_in[2];
    const float* x_mean   = (const float*)d_in[3];
    const float* x_std    = (const float*)d_in[4];
    const float* logdeg   = (const float*)d_in[5];
    const float* W1       = (const float*)d_in[6];
    const float* b1       = (const float*)d_in[7];
    const float* bn_gamma = (const float*)d_in[8];
    const float* bn_beta  = (const float*)d_in[9];
    const float* bn_mean  = (const float*)d_in[10];
    const float* bn_var   = (const float*)d_in[11];
    const float* W2       = (const float*)d_in[12];
    const float* b2       = (const float*)d_in[13];
    const float* SW1      = (const float*)d_in[14];
    const float* Sb1      = (const float*)d_in[15];
    const float* SW2      = (const float*)d_in[16];
    const float* Sb2      = (const float*)d_in[17];
    const float* SW3      = (const float*)d_in[18];
    const float* Sb3      = (const float*)d_in[19];

    float* outp = (float*)d_out;

    // ws layout
    char* wsb = (char*)d_ws;
    float* zbuf = (float*)wsb;                          // 51,200,000 B
    u16* w1h = (u16*)(wsb + 51200000);                  // 262144 B
    u16* w1l = (u16*)(wsb + 51462144);                  // 262144 B
    u16* w2h = (u16*)(wsb + 51724288);                  // 65536 B
    u16* w2l = (u16*)(wsb + 51789824);                  // 65536 B

    prep_weights<<<640, 256, 0, stream>>>(SW1, SW2, w1h, w1l, w2h, w2l);

    node_mlp_kernel<<<N_NODES / TA, 256, 0, stream>>>(
        x, x_mean, x_std, W1, b1, bn_gamma, bn_beta, bn_mean, bn_var, W2, b2, zbuf);

    pair_mfma_kernel<<<(N_PAIRS + PBM - 1) / PBM, 512, 0, stream>>>(
        zbuf, pairs, logdeg, w1h, w1l, w2h, w2l, SW1, Sb1, Sb2, SW3, Sb3, outp);
}

// Round 10
// 624.862 us; speedup vs baseline: 1.0381x; 1.0381x over previous
//
#include <hip/hip_runtime.h>
#include <hip/hip_bf16.h>
#include <math.h>

typedef unsigned short u16;
typedef __attribute__((ext_vector_type(8))) short bf16x8;
typedef __attribute__((ext_vector_type(4))) float f32x4;
typedef __attribute__((ext_vector_type(4))) unsigned u32x4;
typedef __attribute__((ext_vector_type(2))) unsigned u32x2;

#define N_NODES 100000
#define IN_CH 128
#define HID 256
#define EMB 128
#define N_PAIRS 500000
#define BN_EPS 1e-5f

#define TA 32   // nodes per block (kernel A)
#define PBM 64  // pairs per block (kernel B)

// ---- bf16 helpers ----
__device__ __forceinline__ u16 f2bf(float f) {            // scalar RNE (prep kernel)
    unsigned u = __builtin_bit_cast(unsigned, f);
    unsigned r = u + 0x7FFFu + ((u >> 16) & 1u);
    return (u16)(r >> 16);
}
__device__ __forceinline__ float bf2f(u16 h) {
    unsigned u = ((unsigned)h) << 16;
    return __builtin_bit_cast(float, u);
}
// packed pair conversion -> v_cvt_pk_bf16_f32
__device__ __forceinline__ unsigned pk2(float a, float b) {
    __hip_bfloat162 h = __float22bfloat162_rn(make_float2(a, b));
    unsigned u;
    __builtin_memcpy(&u, &h, sizeof(u));
    return u;
}
__device__ __forceinline__ float lo16f(unsigned u) { return __builtin_bit_cast(float, u << 16); }
__device__ __forceinline__ float hi16f(unsigned u) { return __builtin_bit_cast(float, u & 0xffff0000u); }

// ---------------------------------------------------------------------------
// Weight prep into MFMA A-operand fragment-linear layout (weights on M-side):
// idx = ((mt*KS + ks)*64 + l)*8 + j ; value = W[k][n], n = mt*16 + (l&15),
// k = ks*32 + (l>>4)*8 + j.
// ---------------------------------------------------------------------------
__global__ __launch_bounds__(256) void prep_weights(
    const float* __restrict__ SW1, const float* __restrict__ SW2,
    u16* __restrict__ w1h, u16* __restrict__ w1l,
    u16* __restrict__ w2h, u16* __restrict__ w2l)
{
    const int tid = blockIdx.x * 256 + threadIdx.x;
    if (tid < 131072) {                       // W1^T frags: 16 mt x 16 ks
        const int j = tid & 7, l = (tid >> 3) & 63, ks = (tid >> 9) & 15, mt = tid >> 13;
        const int n = mt * 16 + (l & 15);
        const int k = ks * 32 + ((l >> 4) << 3) + j;
        const float v = SW1[(size_t)k * HID + n];
        const u16 h = f2bf(v);
        w1h[tid] = h;
        w1l[tid] = f2bf(v - bf2f(h));
    } else if (tid < 131072 + 32768) {        // W2^T frags: 8 mt x 8 ks
        const int t2 = tid - 131072;
        const int j = t2 & 7, l = (t2 >> 3) & 63, ks = (t2 >> 9) & 7, mt = t2 >> 12;
        const int n = mt * 16 + (l & 15);
        const int k = ks * 32 + ((l >> 4) << 3) + j;
        const float v = SW2[(size_t)k * (HID / 2) + n];
        const u16 h = f2bf(v);
        w2h[t2] = h;
        w2l[t2] = f2bf(v - bf2f(h));
    }
}

// ---------------------------------------------------------------------------
// Kernel A: z = relu( relu(BN(clip((x-mean)/std) @ W1 + b1)) @ W2 + b2 )
// (unchanged — fp32 register-tiled)
// ---------------------------------------------------------------------------
__global__ __launch_bounds__(256) void node_mlp_kernel(
    const float* __restrict__ x,
    const float* __restrict__ x_mean,
    const float* __restrict__ x_std,
    const float* __restrict__ W1,
    const float* __restrict__ b1,
    const float* __restrict__ bn_gamma,
    const float* __restrict__ bn_beta,
    const float* __restrict__ bn_mean,
    const float* __restrict__ bn_var,
    const float* __restrict__ W2,
    const float* __restrict__ b2,
    float* __restrict__ z)
{
    __shared__ __align__(16) float xfT[IN_CH][36];
    __shared__ __align__(16) float hT[HID][36];

    const int t  = threadIdx.x;
    const int n0 = blockIdx.x * TA;

    for (int f = t; f < TA * (IN_CH / 4); f += 256) {
        const int n  = f >> 5;
        const int cg = f & 31;
        float4 v = *reinterpret_cast<const float4*>(x + (size_t)(n0 + n) * IN_CH + cg * 4);
        float vv[4] = {v.x, v.y, v.z, v.w};
        #pragma unroll
        for (int e = 0; e < 4; ++e) {
            const int c = cg * 4 + e;
            float val = vv[e];
            if (!isfinite(val)) val = 0.0f;
            val = (val - x_mean[c]) / x_std[c];
            val = fminf(fmaxf(val, -10.0f), 10.0f);
            xfT[c][n] = val;
        }
    }
    __syncthreads();

    const int i0 = t >> 6;
    const int j  = t & 63;

    {
        float acc[8][4];
        #pragma unroll
        for (int r = 0; r < 8; ++r)
            #pragma unroll
            for (int c = 0; c < 4; ++c) acc[r][c] = 0.0f;

        #pragma unroll 4
        for (int k = 0; k < IN_CH; ++k) {
            float a[8];
            *reinterpret_cast<float4*>(&a[0]) = *reinterpret_cast<const float4*>(&xfT[k][i0 * 8]);
            *reinterpret_cast<float4*>(&a[4]) = *reinterpret_cast<const float4*>(&xfT[k][i0 * 8 + 4]);
            float w[4];
            *reinterpret_cast<float4*>(w) = *reinterpret_cast<const float4*>(W1 + (size_t)k * HID + j * 4);
            #pragma unroll
            for (int r = 0; r < 8; ++r)
                #pragma unroll
                for (int c = 0; c < 4; ++c)
                    acc[r][c] = fmaf(a[r], w[c], acc[r][c]);
        }

        float b1v[4], gv[4], bev[4], mv[4], vv[4];
        *reinterpret_cast<float4*>(b1v) = *reinterpret_cast<const float4*>(b1 + j * 4);
        *reinterpret_cast<float4*>(gv)  = *reinterpret_cast<const float4*>(bn_gamma + j * 4);
        *reinterpret_cast<float4*>(bev) = *reinterpret_cast<const float4*>(bn_beta + j * 4);
        *reinterpret_cast<float4*>(mv)  = *reinterpret_cast<const float4*>(bn_mean + j * 4);
        *reinterpret_cast<float4*>(vv)  = *reinterpret_cast<const float4*>(bn_var + j * 4);

        #pragma unroll
        for (int c = 0; c < 4; ++c) {
            const float scale = gv[c] * rsqrtf(vv[c] + BN_EPS);
            float tmp[8];
            #pragma unroll
            for (int r = 0; r < 8; ++r) {
                const float hv = (acc[r][c] + b1v[c] - mv[c]) * scale + bev[c];
                tmp[r] = fmaxf(hv, 0.0f);
            }
            *reinterpret_cast<float4*>(&hT[j * 4 + c][i0 * 8])     = *reinterpret_cast<float4*>(&tmp[0]);
            *reinterpret_cast<float4*>(&hT[j * 4 + c][i0 * 8 + 4]) = *reinterpret_cast<float4*>(&tmp[4]);
        }
    }
    __syncthreads();

    {
        float acc[8][2];
        #pragma unroll
        for (int r = 0; r < 8; ++r) { acc[r][0] = 0.0f; acc[r][1] = 0.0f; }

        #pragma unroll 4
        for (int k = 0; k < HID; ++k) {
            float a[8];
            *reinterpret_cast<float4*>(&a[0]) = *reinterpret_cast<const float4*>(&hT[k][i0 * 8]);
            *reinterpret_cast<float4*>(&a[4]) = *reinterpret_cast<const float4*>(&hT[k][i0 * 8 + 4]);
            const float2 w = *reinterpret_cast<const float2*>(W2 + (size_t)k * EMB + j * 2);
            #pragma unroll
            for (int r = 0; r < 8; ++r) {
                acc[r][0] = fmaf(a[r], w.x, acc[r][0]);
                acc[r][1] = fmaf(a[r], w.y, acc[r][1]);
            }
        }
        const float2 b2v = *reinterpret_cast<const float2*>(b2 + j * 2);
        #pragma unroll
        for (int r = 0; r < 8; ++r) {
            float2 o;
            o.x = fmaxf(acc[r][0] + b2v.x, 0.0f);
            o.y = fmaxf(acc[r][1] + b2v.y, 0.0f);
            *reinterpret_cast<float2*>(z + (size_t)(n0 + i0 * 8 + r) * EMB + j * 2) = o;
        }
    }
}

// ---------------------------------------------------------------------------
// Kernel B (MFMA): 64 pairs/block, 4 waves (256 thr), DOUBLE-BUFFERED 2x32KB
// LDS segments so every stage/rebuild overlaps an MFMA pass (T3/T14), plus
// weight register-dbuf across sl and setprio(1) around MFMA bursts (T5).
// Schedule:
//   stage sd(ch0:64)->Abuf; ISSUE gather(ch64:128) loads; bar
//   pass(A: ks 0,1,4,5); rebuild(A)->Bbuf(p,ad);            bar
//   write held gather -> Abuf(sd ch64:128); pass(B: 8,9,12,13);  bar
//   pass(A: 2,3,6,7); rebuild(A)->Bbuf;                     bar
//   pass(B: 10,11,14,15)
//   epi1 g=0 -> Abuf; bar; { mfma2(A) || epi1 g=1 -> Bbuf }; bar; mfma2(B)
// ---------------------------------------------------------------------------
__global__ __launch_bounds__(256) void pair_mfma_kernel(
    const float* __restrict__ z,
    const int* __restrict__ pairs,
    const float* __restrict__ logdeg,
    const u16* __restrict__ w1h, const u16* __restrict__ w1l,
    const u16* __restrict__ w2h, const u16* __restrict__ w2l,
    const float* __restrict__ SW1, const float* __restrict__ Sb1,
    const float* __restrict__ Sb2,
    const float* __restrict__ SW3, const float* __restrict__ Sb3,
    float* __restrict__ out)
{
    __shared__ __align__(16) u16 Abuf[2 * 8192];   // 32 KB: hi[0,8192), lo[8192,16384)
    __shared__ __align__(16) u16 Bbuf[2 * 8192];   // 32 KB
    __shared__ float red[4][4][16];                // 1 KB

    const int t   = threadIdx.x;
    const int w   = t >> 6;        // wave 0..3
    const int l   = t & 63;
    const int l15 = l & 15;
    const int l4  = l >> 4;
    const int p0  = blockIdx.x * PBM;

    // split 8 floats and store hi/lo u32x4 into buffer at u16-index base
    #define SPLIT_STORE8(buf, vals, base) { \
        u32x4 hv, lv; \
        _Pragma("unroll") \
        for (int q = 0; q < 4; ++q) { \
            const float a = (vals)[2 * q]; \
            const float b = (vals)[2 * q + 1]; \
            const unsigned hw = pk2(a, b); \
            hv[q] = hw; \
            lv[q] = pk2(a - lo16f(hw), b - hi16f(hw)); \
        } \
        *reinterpret_cast<u32x4*>(&(buf)[(base)])        = hv; \
        *reinterpret_cast<u32x4*>(&(buf)[8192 + (base)]) = lv; }

    // thread (w,l): pair l, channels [w*16, w*16+16) of a 64-ch half.
    // s-type -> slot w>>1 ; d-type -> slot 2+(w>>1) ; q = (w&1)*2 + e
    const int qb  = (w & 1) * 2;
    const int bS0 = (((w >> 1)) * 4 + l4) * 512 + (l15 + 16 * (qb + 0)) * 8;
    const int bS1 = (((w >> 1)) * 4 + l4) * 512 + (l15 + 16 * (qb + 1)) * 8;
    const int bD0 = ((2 + (w >> 1)) * 4 + l4) * 512 + (l15 + 16 * (qb + 0)) * 8;
    const int bD1 = ((2 + (w >> 1)) * 4 + l4) * 512 + (l15 + 16 * (qb + 1)) * 8;

    const int gp  = (p0 + l < N_PAIRS) ? (p0 + l) : (N_PAIRS - 1);
    const int gsi = pairs[(size_t)gp * 2 + 0];
    const int gdi = pairs[(size_t)gp * 2 + 1];

    // ---- stage sd(ch 0:64) -> Abuf ----
    {
        const float* zs = z + (size_t)gsi * EMB + w * 16;
        const float* zd = z + (size_t)gdi * EMB + w * 16;
        float sv[16], dv[16];
        #pragma unroll
        for (int q = 0; q < 4; ++q) {
            *reinterpret_cast<float4*>(&sv[q * 4]) = *reinterpret_cast<const float4*>(zs + q * 4);
            *reinterpret_cast<float4*>(&dv[q * 4]) = *reinterpret_cast<const float4*>(zd + q * 4);
        }
        SPLIT_STORE8(Abuf, sv + 0, bS0);
        SPLIT_STORE8(Abuf, sv + 8, bS1);
        SPLIT_STORE8(Abuf, dv + 0, bD0);
        SPLIT_STORE8(Abuf, dv + 8, bD1);
    }

    // ---- ISSUE gather(ch 64:128) loads now; consumed after pass(A) (T14) ----
    float s1r[16], d1r[16];
    {
        const float* zs = z + (size_t)gsi * EMB + 64 + w * 16;
        const float* zd = z + (size_t)gdi * EMB + 64 + w * 16;
        #pragma unroll
        for (int q = 0; q < 4; ++q) {
            *reinterpret_cast<float4*>(&s1r[q * 4]) = *reinterpret_cast<const float4*>(zs + q * 4);
            *reinterpret_cast<float4*>(&d1r[q * 4]) = *reinterpret_cast<const float4*>(zd + q * 4);
        }
    }

    // ---- prefetch epilogue-1 gather data ----
    float ldS[4], ldD[4];
    #pragma unroll
    for (int nt = 0; nt < 4; ++nt) {
        const int pidx = (p0 + nt * 16 + l15 < N_PAIRS) ? (p0 + nt * 16 + l15) : (N_PAIRS - 1);
        ldS[nt] = logdeg[pairs[(size_t)pidx * 2 + 0]];
        ldD[nt] = logdeg[pairs[(size_t)pidx * 2 + 1]];
    }

    __syncthreads();   // bar1: Abuf(sd ch0:64) visible

    // ---- layer 1 accumulators: wave w owns mt {4w..4w+3} ----
    f32x4 acc[4][4];
    #pragma unroll
    for (int m = 0; m < 4; ++m)
        #pragma unroll
        for (int nt = 0; nt < 4; ++nt) acc[m][nt] = (f32x4){0.f, 0.f, 0.f, 0.f};

    // one 128-K segment from buf; slots 0..3 use weight ks {k0..k3};
    // weight register double-buffer across sl; setprio around MFMA bursts
    auto run_pass = [&](const u16* buf, int k0, int k1, int k2, int k3) {
        const int ksg[4] = {k0, k1, k2, k3};
        bf16x8 wh[2][4], wl[2][4];
        #pragma unroll
        for (int m = 0; m < 4; ++m) {
            const size_t bo = ((size_t)((w * 4 + m) * 16 + ksg[0]) * 64 + l) * 8;
            wh[0][m] = *reinterpret_cast<const bf16x8*>(&w1h[bo]);
            wl[0][m] = *reinterpret_cast<const bf16x8*>(&w1l[bo]);
        }
        #pragma unroll
        for (int sl = 0; sl < 4; ++sl) {
            const int cur = sl & 1;
            if (sl < 3) {
                #pragma unroll
                for (int m = 0; m < 4; ++m) {
                    const size_t bo = ((size_t)((w * 4 + m) * 16 + ksg[sl + 1]) * 64 + l) * 8;
                    wh[cur ^ 1][m] = *reinterpret_cast<const bf16x8*>(&w1h[bo]);
                    wl[cur ^ 1][m] = *reinterpret_cast<const bf16x8*>(&w1l[bo]);
                }
            }
            #pragma unroll
            for (int nh = 0; nh < 2; ++nh) {
                bf16x8 fh[2], fl[2];
                #pragma unroll
                for (int e = 0; e < 2; ++e) {
                    const int fb = (sl * 4 + nh * 2 + e) * 512 + l * 8;
                    fh[e] = *reinterpret_cast<const bf16x8*>(&buf[fb]);
                    fl[e] = *reinterpret_cast<const bf16x8*>(&buf[8192 + fb]);
                }
                __builtin_amdgcn_s_setprio(1);
                #pragma unroll
                for (int m = 0; m < 4; ++m)
                    #pragma unroll
                    for (int e = 0; e < 2; ++e)
                        acc[m][nh * 2 + e] = __builtin_amdgcn_mfma_f32_16x16x32_bf16(wh[cur][m], fh[e], acc[m][nh * 2 + e], 0, 0, 0);
                #pragma unroll
                for (int m = 0; m < 4; ++m)
                    #pragma unroll
                    for (int e = 0; e < 2; ++e)
                        acc[m][nh * 2 + e] = __builtin_amdgcn_mfma_f32_16x16x32_bf16(wl[cur][m], fh[e], acc[m][nh * 2 + e], 0, 0, 0);
                #pragma unroll
                for (int m = 0; m < 4; ++m)
                    #pragma unroll
                    for (int e = 0; e < 2; ++e)
                        acc[m][nh * 2 + e] = __builtin_amdgcn_mfma_f32_16x16x32_bf16(wh[cur][m], fl[e], acc[m][nh * 2 + e], 0, 0, 0);
                __builtin_amdgcn_s_setprio(0);
            }
        }
    };

    // rebuild from buf's own-lane quantized s~,d~: p = s~*d~, ad = |s~-d~|
    auto rebuild = [&](const u16* buf, float* pv, float* av) {
        const int bases[2] = {bS0, bS1};
        const int based[2] = {bD0, bD1};
        #pragma unroll
        for (int e = 0; e < 2; ++e) {
            u32x4 sh = *reinterpret_cast<const u32x4*>(&buf[bases[e]]);
            u32x4 sl = *reinterpret_cast<const u32x4*>(&buf[8192 + bases[e]]);
            u32x4 dh = *reinterpret_cast<const u32x4*>(&buf[based[e]]);
            u32x4 dl = *reinterpret_cast<const u32x4*>(&buf[8192 + based[e]]);
            #pragma unroll
            for (int qq = 0; qq < 4; ++qq) {
                const float s0 = lo16f(sh[qq]) + lo16f(sl[qq]);
                const float s1 = hi16f(sh[qq]) + hi16f(sl[qq]);
                const float d0 = lo16f(dh[qq]) + lo16f(dl[qq]);
                const float d1 = hi16f(dh[qq]) + hi16f(dl[qq]);
                pv[e * 8 + 2 * qq]     = s0 * d0;
                pv[e * 8 + 2 * qq + 1] = s1 * d1;
                av[e * 8 + 2 * qq]     = fabsf(s0 - d0);
                av[e * 8 + 2 * qq + 1] = fabsf(s1 - d1);
            }
        }
    };

    // ---- seg0 compute + rebuild -> Bbuf ----
    run_pass(Abuf, 0, 1, 4, 5);
    {
        float pv[16], av[16];
        rebuild(Abuf, pv, av);
        SPLIT_STORE8(Bbuf, pv + 0, bS0);
        SPLIT_STORE8(Bbuf, pv + 8, bS1);
        SPLIT_STORE8(Bbuf, av + 0, bD0);
        SPLIT_STORE8(Bbuf, av + 8, bD1);
    }
    __syncthreads();   // bar2: Bbuf(p,ad ch0:64) visible; all done reading Abuf seg0

    // ---- write held gather(ch64:128) -> Abuf, then compute seg2 from Bbuf ----
    SPLIT_STORE8(Abuf, s1r + 0, bS0);
    SPLIT_STORE8(Abuf, s1r + 8, bS1);
    SPLIT_STORE8(Abuf, d1r + 0, bD0);
    SPLIT_STORE8(Abuf, d1r + 8, bD1);
    run_pass(Bbuf, 8, 9, 12, 13);
    __syncthreads();   // bar3: Abuf(sd ch64:128) visible; all done reading Bbuf

    // ---- seg1 compute + rebuild -> Bbuf ----
    run_pass(Abuf, 2, 3, 6, 7);
    {
        float pv[16], av[16];
        rebuild(Abuf, pv, av);
        SPLIT_STORE8(Bbuf, pv + 0, bS0);
        SPLIT_STORE8(Bbuf, pv + 8, bS1);
        SPLIT_STORE8(Bbuf, av + 0, bD0);
        SPLIT_STORE8(Bbuf, av + 8, bD1);
    }
    __syncthreads();   // bar4: Bbuf(p,ad ch64:128) visible; done reading Abuf seg1

    // ---- seg3 compute ----
    run_pass(Bbuf, 10, 11, 14, 15);

    // ---- layer 2: epi1 g=0 -> Abuf, bar, { mfma2(A) || epi1 g=1 -> Bbuf }, bar, mfma2(B) ----
    f32x4 acc2[2][4];
    #pragma unroll
    for (int m2 = 0; m2 < 2; ++m2)
        #pragma unroll
        for (int nt = 0; nt < 4; ++nt) acc2[m2][nt] = (f32x4){0.f, 0.f, 0.f, 0.f};

    // epilogue-1 for m in {2g, 2g+1}: bias + logdeg rank-2 + relu -> s1 frags
    auto epi1 = [&](u16* buf, int g) {
        #pragma unroll
        for (int mm = 0; mm < 2; ++mm) {
            const int m  = 2 * g + mm;
            const int mt = w * 4 + m;
            const int nb = mt * 16 + l4 * 4;
            float sb[4], wa[4], wb[4];
            *reinterpret_cast<float4*>(sb) = *reinterpret_cast<const float4*>(&Sb1[nb]);
            *reinterpret_cast<float4*>(wa) = *reinterpret_cast<const float4*>(&SW1[(size_t)512 * HID + nb]);
            *reinterpret_cast<float4*>(wb) = *reinterpret_cast<const float4*>(&SW1[(size_t)513 * HID + nb]);
            #pragma unroll
            for (int nt = 0; nt < 4; ++nt) {
                float v[4];
                #pragma unroll
                for (int r = 0; r < 4; ++r) {
                    float x0 = acc[m][nt][r] + sb[r];
                    x0 = fmaf(ldS[nt], wa[r], x0);
                    x0 = fmaf(ldD[nt], wb[r], x0);
                    v[r] = fmaxf(x0, 0.0f);
                }
                const unsigned h0 = pk2(v[0], v[1]);
                const unsigned h1 = pk2(v[2], v[3]);
                u32x2 hv, lv;
                hv[0] = h0; hv[1] = h1;
                lv[0] = pk2(v[0] - lo16f(h0), v[1] - hi16f(h0));
                lv[1] = pk2(v[2] - lo16f(h1), v[3] - hi16f(h1));
                const int base = (w * 4 + nt) * 512
                               + (l15 + 16 * ((m & 1) * 2 + (l4 >> 1))) * 8
                               + (l4 & 1) * 4;
                *reinterpret_cast<u32x2*>(&buf[base])        = hv;
                *reinterpret_cast<u32x2*>(&buf[8192 + base]) = lv;
            }
        }
    };

    // mfma2 over a staged buffer: slot cs holds ks2 = 2cs + g
    auto mfma2 = [&](const u16* buf, int g) {
        #pragma unroll
        for (int cs = 0; cs < 4; ++cs) {
            const int ks2 = cs * 2 + g;
            bf16x8 wh2[2], wl2[2];
            #pragma unroll
            for (int m2 = 0; m2 < 2; ++m2) {
                const size_t bo = ((size_t)((w * 2 + m2) * 8 + ks2) * 64 + l) * 8;
                wh2[m2] = *reinterpret_cast<const bf16x8*>(&w2h[bo]);
                wl2[m2] = *reinterpret_cast<const bf16x8*>(&w2l[bo]);
            }
            #pragma unroll
            for (int nh = 0; nh < 2; ++nh) {
                bf16x8 fh[2], fl[2];
                #pragma unroll
                for (int e = 0; e < 2; ++e) {
                    const int fb = (cs * 4 + nh * 2 + e) * 512 + l * 8;
                    fh[e] = *reinterpret_cast<const bf16x8*>(&buf[fb]);
                    fl[e] = *reinterpret_cast<const bf16x8*>(&buf[8192 + fb]);
                }
                __builtin_amdgcn_s_setprio(1);
                #pragma unroll
                for (int m2 = 0; m2 < 2; ++m2)
                    #pragma unroll
                    for (int e = 0; e < 2; ++e)
                        acc2[m2][nh * 2 + e] = __builtin_amdgcn_mfma_f32_16x16x32_bf16(wh2[m2], fh[e], acc2[m2][nh * 2 + e], 0, 0, 0);
                #pragma unroll
                for (int m2 = 0; m2 < 2; ++m2)
                    #pragma unroll
                    for (int e = 0; e < 2; ++e)
                        acc2[m2][nh * 2 + e] = __builtin_amdgcn_mfma_f32_16x16x32_bf16(wl2[m2], fh[e], acc2[m2][nh * 2 + e], 0, 0, 0);
                #pragma unroll
                for (int m2 = 0; m2 < 2; ++m2)
                    #pragma unroll
                    for (int e = 0; e < 2; ++e)
                        acc2[m2][nh * 2 + e] = __builtin_amdgcn_mfma_f32_16x16x32_bf16(wh2[m2], fl[e], acc2[m2][nh * 2 + e], 0, 0, 0);
                __builtin_amdgcn_s_setprio(0);
            }
        }
    };

    epi1(Abuf, 0);           // Abuf last read at bar4-guarded pass; safe to overwrite
    __syncthreads();         // bar5: Abuf g=0 frags visible; all done reading Bbuf seg3
    epi1(Bbuf, 1);           // overlaps mfma2(A) issue below (independent)
    mfma2(Abuf, 0);
    __syncthreads();         // bar6: Bbuf g=1 frags visible; done reading Abuf
    mfma2(Bbuf, 1);

    // ---- epilogue 2 + layer 3: register dot with SW3, cross-lane+wave reduce ----
    {
        float part[4] = {0.f, 0.f, 0.f, 0.f};
        #pragma unroll
        for (int m2 = 0; m2 < 2; ++m2) {
            const int nb2 = (w * 2 + m2) * 16 + l4 * 4;
            float sb[4], w3[4];
            *reinterpret_cast<float4*>(sb) = *reinterpret_cast<const float4*>(&Sb2[nb2]);
            *reinterpret_cast<float4*>(w3) = *reinterpret_cast<const float4*>(&SW3[nb2]);
            #pragma unroll
            for (int nt = 0; nt < 4; ++nt)
                #pragma unroll
                for (int r = 0; r < 4; ++r)
                    part[nt] = fmaf(fmaxf(acc2[m2][nt][r] + sb[r], 0.0f), w3[r], part[nt]);
        }
        #pragma unroll
        for (int nt = 0; nt < 4; ++nt) {
            part[nt] += __shfl_xor(part[nt], 16);
            part[nt] += __shfl_xor(part[nt], 32);
        }
        if (l < 16) {
            #pragma unroll
            for (int nt = 0; nt < 4; ++nt) red[w][nt][l15] = part[nt];
        }
    }
    __syncthreads();   // bar7

    if (t < 64) {
        const int nt = t >> 4, pp = t & 15;
        float v = red[0][nt][pp] + red[1][nt][pp] + red[2][nt][pp] + red[3][nt][pp] + Sb3[0];
        if (isnan(v)) v = 0.0f;
        else if (isinf(v)) v = (v > 0.0f) ? 20.0f : -20.0f;
        const int pidx = p0 + nt * 16 + pp;
        if (pidx < N_PAIRS) out[pidx] = v;
    }
    #undef SPLIT_STORE8
}

// ---------------------------------------------------------------------------
extern "C" void kernel_launch(void* const* d_in, const int* in_sizes, int n_in,
                              void* d_out, int out_size, void* d_ws, size_t ws_size,
                              hipStream_t stream)
{
    const float* x        = (const float*)d_in[0];
    // d_in[1] = edge_index : unused by the reference
    const int*   pairs    = (const int*)d_in[2];
    const float* x_mean   = (const float*)d_in[3];
    const float* x_std    = (const float*)d_in[4];
    const float* logdeg   = (const float*)d_in[5];
    const float* W1       = (const float*)d_in[6];
    const float* b1       = (const float*)d_in[7];
    const float* bn_gamma = (const float*)d_in[8];
    const float* bn_beta  = (const float*)d_in[9];
    const float* bn_mean  = (const float*)d_in[10];
    const float* bn_var   = (const float*)d_in[11];
    const float* W2       = (const float*)d_in[12];
    const float* b2       = (const float*)d_in[13];
    const float* SW1      = (const float*)d_in[14];
    const float* Sb1      = (const float*)d_in[15];
    const float* SW2      = (const float*)d_in[16];
    const float* Sb2      = (const float*)d_in[17];
    const float* SW3      = (const float*)d_in[18];
    const float* Sb3      = (const float*)d_in[19];

    float* outp = (float*)d_out;

    // ws layout
    char* wsb = (char*)d_ws;
    float* zbuf = (float*)wsb;                          // 51,200,000 B
    u16* w1h = (u16*)(wsb + 51200000);                  // 262144 B
    u16* w1l = (u16*)(wsb + 51462144);                  // 262144 B
    u16* w2h = (u16*)(wsb + 51724288);                  // 65536 B
    u16* w2l = (u16*)(wsb + 51789824);                  // 65536 B

    prep_weights<<<640, 256, 0, stream>>>(SW1, SW2, w1h, w1l, w2h, w2l);

    node_mlp_kernel<<<N_NODES / TA, 256, 0, stream>>>(
        x, x_mean, x_std, W1, b1, bn_gamma, bn_beta, bn_mean, bn_var, W2, b2, zbuf);

    pair_mfma_kernel<<<(N_PAIRS + PBM - 1) / PBM, 256, 0, stream>>>(
        zbuf, pairs, logdeg, w1h, w1l, w2h, w2l, SW1, Sb1, Sb2, SW3, Sb3, outp);
}

// Round 11
// 385.993 us; speedup vs baseline: 1.6805x; 1.6188x over previous
//
#include <hip/hip_runtime.h>
#include <hip/hip_bf16.h>
#include <math.h>

typedef unsigned short u16;
typedef __attribute__((ext_vector_type(8))) short bf16x8;
typedef __attribute__((ext_vector_type(4))) float f32x4;
typedef __attribute__((ext_vector_type(4))) unsigned u32x4;
typedef __attribute__((ext_vector_type(2))) unsigned u32x2;

#define N_NODES 100000
#define IN_CH 128
#define HID 256
#define EMB 128
#define N_PAIRS 500000
#define BN_EPS 1e-5f

#define PBM 64  // pairs per block (kernel B); also 64 nodes/block (kernel A)

// ---- bf16 helpers ----
__device__ __forceinline__ u16 f2bf(float f) {            // scalar RNE (prep kernel)
    unsigned u = __builtin_bit_cast(unsigned, f);
    unsigned r = u + 0x7FFFu + ((u >> 16) & 1u);
    return (u16)(r >> 16);
}
__device__ __forceinline__ float bf2f(u16 h) {
    unsigned u = ((unsigned)h) << 16;
    return __builtin_bit_cast(float, u);
}
// packed pair conversion -> v_cvt_pk_bf16_f32
__device__ __forceinline__ unsigned pk2(float a, float b) {
    __hip_bfloat162 h = __float22bfloat162_rn(make_float2(a, b));
    unsigned u;
    __builtin_memcpy(&u, &h, sizeof(u));
    return u;
}
__device__ __forceinline__ float lo16f(unsigned u) { return __builtin_bit_cast(float, u << 16); }
__device__ __forceinline__ float hi16f(unsigned u) { return __builtin_bit_cast(float, u & 0xffff0000u); }

// store 8 floats as bf16 (hi only) at u16-index base
__device__ __forceinline__ void store8(u16* buf, int base, const float* v) {
    u32x4 hv;
    #pragma unroll
    for (int q = 0; q < 4; ++q) hv[q] = pk2(v[2 * q], v[2 * q + 1]);
    *reinterpret_cast<u32x4*>(&buf[base]) = hv;
}

// ---------------------------------------------------------------------------
// Weight prep into MFMA A-operand fragment-linear layout (weights on M-side):
// idx = ((mt*KS + ks)*64 + l)*8 + j ; value = W[k][n], n = mt*16 + (l&15),
// k = ks*32 + (l>>4)*8 + j. Covers SW1 (16x16), SW2 (8x8), W1 (16x4), W2 (8x8).
// ---------------------------------------------------------------------------
__global__ __launch_bounds__(256) void prep_weights(
    const float* __restrict__ SW1, const float* __restrict__ SW2,
    const float* __restrict__ W1,  const float* __restrict__ W2,
    u16* __restrict__ w1h, u16* __restrict__ w1l,
    u16* __restrict__ w2h, u16* __restrict__ w2l,
    u16* __restrict__ w1nh, u16* __restrict__ w1nl,
    u16* __restrict__ w2nh, u16* __restrict__ w2nl)
{
    const int tid = blockIdx.x * 256 + threadIdx.x;
    if (tid < 131072) {                       // SW1 frags: 16 mt x 16 ks
        const int j = tid & 7, l = (tid >> 3) & 63, ks = (tid >> 9) & 15, mt = tid >> 13;
        const int n = mt * 16 + (l & 15);
        const int k = ks * 32 + ((l >> 4) << 3) + j;
        const float v = SW1[(size_t)k * HID + n];
        const u16 h = f2bf(v);
        w1h[tid] = h;
        w1l[tid] = f2bf(v - bf2f(h));
    } else if (tid < 163840) {                // SW2 frags: 8 mt x 8 ks
        const int t2 = tid - 131072;
        const int j = t2 & 7, l = (t2 >> 3) & 63, ks = (t2 >> 9) & 7, mt = t2 >> 12;
        const int n = mt * 16 + (l & 15);
        const int k = ks * 32 + ((l >> 4) << 3) + j;
        const float v = SW2[(size_t)k * (HID / 2) + n];
        const u16 h = f2bf(v);
        w2h[t2] = h;
        w2l[t2] = f2bf(v - bf2f(h));
    } else if (tid < 196608) {                // W1 node frags: 16 mt x 4 ks
        const int t3 = tid - 163840;
        const int j = t3 & 7, l = (t3 >> 3) & 63, ks = (t3 >> 9) & 3, mt = t3 >> 11;
        const int n = mt * 16 + (l & 15);
        const int k = ks * 32 + ((l >> 4) << 3) + j;
        const float v = W1[(size_t)k * HID + n];
        const u16 h = f2bf(v);
        w1nh[t3] = h;
        w1nl[t3] = f2bf(v - bf2f(h));
    } else if (tid < 229376) {                // W2 node frags: 8 mt x 8 ks
        const int t4 = tid - 196608;
        const int j = t4 & 7, l = (t4 >> 3) & 63, ks = (t4 >> 9) & 7, mt = t4 >> 12;
        const int n = mt * 16 + (l & 15);
        const int k = ks * 32 + ((l >> 4) << 3) + j;
        const float v = W2[(size_t)k * EMB + n];
        const u16 h = f2bf(v);
        w2nh[t4] = h;
        w2nl[t4] = f2bf(v - bf2f(h));
    }
}

// ---------------------------------------------------------------------------
// Kernel A (MFMA): node MLP. 64 nodes/block, 4 waves.
//   L1: h = relu(BN(xf @ W1 + b1)), K=128 (4 slots), 2-product split.
//   L2: z = relu(h @ W2 + b2),      K=256 (8 slots), 2-product split.
// xf staged bf16 in XF; h staged bf16 in HF (ks2-major frag layout).
// ---------------------------------------------------------------------------
__global__ __launch_bounds__(256) void node_mfma_kernel(
    const float* __restrict__ x,
    const float* __restrict__ x_mean, const float* __restrict__ x_std,
    const float* __restrict__ b1,
    const float* __restrict__ bn_gamma, const float* __restrict__ bn_beta,
    const float* __restrict__ bn_mean,  const float* __restrict__ bn_var,
    const float* __restrict__ b2,
    const u16* __restrict__ w1nh, const u16* __restrict__ w1nl,
    const u16* __restrict__ w2nh, const u16* __restrict__ w2nl,
    float* __restrict__ z)
{
    __shared__ __align__(16) u16 XF[8192];    // 16 KB: [slot 0..3][nt 0..3][512]
    __shared__ __align__(16) u16 HF[16384];   // 32 KB: [ks2 0..7][nt 0..3][512]

    const int t   = threadIdx.x;
    const int w   = t >> 6;
    const int l   = t & 63;
    const int l15 = l & 15;
    const int l4  = l >> 4;
    const int n0  = blockIdx.x * 64;
    const int nd  = (n0 + l < N_NODES) ? (n0 + l) : (N_NODES - 1);

    // ---- stage xf: thread (w,l) = node l, channels [w*32, w*32+32) ----
    {
        const float* xp = x + (size_t)nd * IN_CH + w * 32;
        float v[32];
        #pragma unroll
        for (int q = 0; q < 8; ++q)
            *reinterpret_cast<float4*>(&v[q * 4]) = *reinterpret_cast<const float4*>(xp + q * 4);
        #pragma unroll
        for (int q = 0; q < 8; ++q) {
            float4 m4 = *reinterpret_cast<const float4*>(x_mean + w * 32 + q * 4);
            float4 s4 = *reinterpret_cast<const float4*>(x_std  + w * 32 + q * 4);
            float mm[4] = {m4.x, m4.y, m4.z, m4.w};
            float ss[4] = {s4.x, s4.y, s4.z, s4.w};
            #pragma unroll
            for (int e = 0; e < 4; ++e) {
                float val = v[q * 4 + e];
                if (!isfinite(val)) val = 0.0f;
                val = (val - mm[e]) / ss[e];
                v[q * 4 + e] = fminf(fmaxf(val, -10.0f), 10.0f);
            }
        }
        #pragma unroll
        for (int q = 0; q < 4; ++q) {
            const int base = (w * 4 + l4) * 512 + (l15 + 16 * q) * 8;
            store8(XF, base, &v[q * 8]);
        }
    }
    __syncthreads();

    // ---- L1: acc[m][nt], wave owns mt {4w..4w+3}, K=128 ----
    f32x4 acc[4][4];
    #pragma unroll
    for (int m = 0; m < 4; ++m)
        #pragma unroll
        for (int nt = 0; nt < 4; ++nt) acc[m][nt] = (f32x4){0.f, 0.f, 0.f, 0.f};

    #pragma unroll
    for (int sl = 0; sl < 4; ++sl) {
        bf16x8 wh[4], wl[4];
        #pragma unroll
        for (int m = 0; m < 4; ++m) {
            const size_t bo = ((size_t)((w * 4 + m) * 4 + sl) * 64 + l) * 8;
            wh[m] = *reinterpret_cast<const bf16x8*>(&w1nh[bo]);
            wl[m] = *reinterpret_cast<const bf16x8*>(&w1nl[bo]);
        }
        bf16x8 fh[4];
        #pragma unroll
        for (int nt = 0; nt < 4; ++nt)
            fh[nt] = *reinterpret_cast<const bf16x8*>(&XF[(sl * 4 + nt) * 512 + l * 8]);
        __builtin_amdgcn_s_setprio(1);
        #pragma unroll
        for (int m = 0; m < 4; ++m)
            #pragma unroll
            for (int nt = 0; nt < 4; ++nt)
                acc[m][nt] = __builtin_amdgcn_mfma_f32_16x16x32_bf16(wh[m], fh[nt], acc[m][nt], 0, 0, 0);
        #pragma unroll
        for (int m = 0; m < 4; ++m)
            #pragma unroll
            for (int nt = 0; nt < 4; ++nt)
                acc[m][nt] = __builtin_amdgcn_mfma_f32_16x16x32_bf16(wl[m], fh[nt], acc[m][nt], 0, 0, 0);
        __builtin_amdgcn_s_setprio(0);
    }

    // ---- epilogue 1: BN + relu -> HF (bf16) ----
    #pragma unroll
    for (int m = 0; m < 4; ++m) {
        const int mt = w * 4 + m;
        const int nb = mt * 16 + l4 * 4;
        float4 b1v = *reinterpret_cast<const float4*>(b1 + nb);
        float4 gv  = *reinterpret_cast<const float4*>(bn_gamma + nb);
        float4 bev = *reinterpret_cast<const float4*>(bn_beta + nb);
        float4 mev = *reinterpret_cast<const float4*>(bn_mean + nb);
        float4 vav = *reinterpret_cast<const float4*>(bn_var + nb);
        float scale[4], shift[4];
        float bb[4] = {b1v.x, b1v.y, b1v.z, b1v.w};
        float gg[4] = {gv.x, gv.y, gv.z, gv.w};
        float be[4] = {bev.x, bev.y, bev.z, bev.w};
        float me[4] = {mev.x, mev.y, mev.z, mev.w};
        float va[4] = {vav.x, vav.y, vav.z, vav.w};
        #pragma unroll
        for (int r = 0; r < 4; ++r) {
            scale[r] = gg[r] * rsqrtf(va[r] + BN_EPS);
            shift[r] = (bb[r] - me[r]) * scale[r] + be[r];
        }
        #pragma unroll
        for (int nt = 0; nt < 4; ++nt) {
            float v[4];
            #pragma unroll
            for (int r = 0; r < 4; ++r)
                v[r] = fmaxf(fmaf(acc[m][nt][r], scale[r], shift[r]), 0.0f);
            u32x2 hv;
            hv[0] = pk2(v[0], v[1]);
            hv[1] = pk2(v[2], v[3]);
            const int base = ((mt >> 1) * 4 + nt) * 512
                           + (l15 + 16 * ((mt & 1) * 2 + (l4 >> 1))) * 8
                           + (l4 & 1) * 4;
            *reinterpret_cast<u32x2*>(&HF[base]) = hv;
        }
    }
    __syncthreads();

    // ---- L2: acc2[m2][nt], wave owns mt2 {2w, 2w+1}, K=256 ----
    f32x4 acc2[2][4];
    #pragma unroll
    for (int m2 = 0; m2 < 2; ++m2)
        #pragma unroll
        for (int nt = 0; nt < 4; ++nt) acc2[m2][nt] = (f32x4){0.f, 0.f, 0.f, 0.f};

    #pragma unroll
    for (int ks2 = 0; ks2 < 8; ++ks2) {
        bf16x8 wh2[2], wl2[2];
        #pragma unroll
        for (int m2 = 0; m2 < 2; ++m2) {
            const size_t bo = ((size_t)((w * 2 + m2) * 8 + ks2) * 64 + l) * 8;
            wh2[m2] = *reinterpret_cast<const bf16x8*>(&w2nh[bo]);
            wl2[m2] = *reinterpret_cast<const bf16x8*>(&w2nl[bo]);
        }
        bf16x8 fh[4];
        #pragma unroll
        for (int nt = 0; nt < 4; ++nt)
            fh[nt] = *reinterpret_cast<const bf16x8*>(&HF[(ks2 * 4 + nt) * 512 + l * 8]);
        __builtin_amdgcn_s_setprio(1);
        #pragma unroll
        for (int m2 = 0; m2 < 2; ++m2)
            #pragma unroll
            for (int nt = 0; nt < 4; ++nt)
                acc2[m2][nt] = __builtin_amdgcn_mfma_f32_16x16x32_bf16(wh2[m2], fh[nt], acc2[m2][nt], 0, 0, 0);
        #pragma unroll
        for (int m2 = 0; m2 < 2; ++m2)
            #pragma unroll
            for (int nt = 0; nt < 4; ++nt)
                acc2[m2][nt] = __builtin_amdgcn_mfma_f32_16x16x32_bf16(wl2[m2], fh[nt], acc2[m2][nt], 0, 0, 0);
        __builtin_amdgcn_s_setprio(0);
    }

    // ---- epilogue 2: z = relu(acc2 + b2) -> global ----
    #pragma unroll
    for (int m2 = 0; m2 < 2; ++m2) {
        const int nb2 = (w * 2 + m2) * 16 + l4 * 4;
        float4 b2v = *reinterpret_cast<const float4*>(b2 + nb2);
        float bb[4] = {b2v.x, b2v.y, b2v.z, b2v.w};
        #pragma unroll
        for (int nt = 0; nt < 4; ++nt) {
            const int node = n0 + nt * 16 + l15;
            if (node < N_NODES) {
                float4 o;
                o.x = fmaxf(acc2[m2][nt][0] + bb[0], 0.0f);
                o.y = fmaxf(acc2[m2][nt][1] + bb[1], 0.0f);
                o.z = fmaxf(acc2[m2][nt][2] + bb[2], 0.0f);
                o.w = fmaxf(acc2[m2][nt][3] + bb[3], 0.0f);
                *reinterpret_cast<float4*>(z + (size_t)node * EMB + nb2) = o;
            }
        }
    }
}

// ---------------------------------------------------------------------------
// Kernel B (MFMA): 64 pairs/block, 4 waves, r10 double-buffered schedule with
// 2-PRODUCT split (exact-split weights x bf16 features): fl dropped entirely.
// Abuf/Bbuf 16 KB each (bf16 hi only). MFMA floor 158 us (was 237).
// ---------------------------------------------------------------------------
__global__ __launch_bounds__(256) void pair_mfma_kernel(
    const float* __restrict__ z,
    const int* __restrict__ pairs,
    const float* __restrict__ logdeg,
    const u16* __restrict__ w1h, const u16* __restrict__ w1l,
    const u16* __restrict__ w2h, const u16* __restrict__ w2l,
    const float* __restrict__ SW1, const float* __restrict__ Sb1,
    const float* __restrict__ Sb2,
    const float* __restrict__ SW3, const float* __restrict__ Sb3,
    float* __restrict__ out)
{
    __shared__ __align__(16) u16 Abuf[8192];   // 16 KB
    __shared__ __align__(16) u16 Bbuf[8192];   // 16 KB
    __shared__ float red[4][4][16];            // 1 KB

    const int t   = threadIdx.x;
    const int w   = t >> 6;        // wave 0..3
    const int l   = t & 63;
    const int l15 = l & 15;
    const int l4  = l >> 4;
    const int p0  = blockIdx.x * PBM;

    // thread (w,l): pair l, channels [w*16, w*16+16) of a 64-ch half.
    const int qb  = (w & 1) * 2;
    const int bS0 = (((w >> 1)) * 4 + l4) * 512 + (l15 + 16 * (qb + 0)) * 8;
    const int bS1 = (((w >> 1)) * 4 + l4) * 512 + (l15 + 16 * (qb + 1)) * 8;
    const int bD0 = ((2 + (w >> 1)) * 4 + l4) * 512 + (l15 + 16 * (qb + 0)) * 8;
    const int bD1 = ((2 + (w >> 1)) * 4 + l4) * 512 + (l15 + 16 * (qb + 1)) * 8;

    const int gp  = (p0 + l < N_PAIRS) ? (p0 + l) : (N_PAIRS - 1);
    const int gsi = pairs[(size_t)gp * 2 + 0];
    const int gdi = pairs[(size_t)gp * 2 + 1];

    // ---- stage sd(ch 0:64) -> Abuf ----
    {
        const float* zs = z + (size_t)gsi * EMB + w * 16;
        const float* zd = z + (size_t)gdi * EMB + w * 16;
        float sv[16], dv[16];
        #pragma unroll
        for (int q = 0; q < 4; ++q) {
            *reinterpret_cast<float4*>(&sv[q * 4]) = *reinterpret_cast<const float4*>(zs + q * 4);
            *reinterpret_cast<float4*>(&dv[q * 4]) = *reinterpret_cast<const float4*>(zd + q * 4);
        }
        store8(Abuf, bS0, sv + 0);
        store8(Abuf, bS1, sv + 8);
        store8(Abuf, bD0, dv + 0);
        store8(Abuf, bD1, dv + 8);
    }

    // ---- ISSUE gather(ch 64:128) loads now; consumed after pass(A) (T14) ----
    float s1r[16], d1r[16];
    {
        const float* zs = z + (size_t)gsi * EMB + 64 + w * 16;
        const float* zd = z + (size_t)gdi * EMB + 64 + w * 16;
        #pragma unroll
        for (int q = 0; q < 4; ++q) {
            *reinterpret_cast<float4*>(&s1r[q * 4]) = *reinterpret_cast<const float4*>(zs + q * 4);
            *reinterpret_cast<float4*>(&d1r[q * 4]) = *reinterpret_cast<const float4*>(zd + q * 4);
        }
    }

    // ---- prefetch epilogue-1 gather data ----
    float ldS[4], ldD[4];
    #pragma unroll
    for (int nt = 0; nt < 4; ++nt) {
        const int pidx = (p0 + nt * 16 + l15 < N_PAIRS) ? (p0 + nt * 16 + l15) : (N_PAIRS - 1);
        ldS[nt] = logdeg[pairs[(size_t)pidx * 2 + 0]];
        ldD[nt] = logdeg[pairs[(size_t)pidx * 2 + 1]];
    }

    __syncthreads();   // bar1

    f32x4 acc[4][4];
    #pragma unroll
    for (int m = 0; m < 4; ++m)
        #pragma unroll
        for (int nt = 0; nt < 4; ++nt) acc[m][nt] = (f32x4){0.f, 0.f, 0.f, 0.f};

    // one 128-K segment; weight register dbuf across sl; 2-product
    auto run_pass = [&](const u16* buf, int k0, int k1, int k2, int k3) {
        const int ksg[4] = {k0, k1, k2, k3};
        bf16x8 wh[2][4], wl[2][4];
        #pragma unroll
        for (int m = 0; m < 4; ++m) {
            const size_t bo = ((size_t)((w * 4 + m) * 16 + ksg[0]) * 64 + l) * 8;
            wh[0][m] = *reinterpret_cast<const bf16x8*>(&w1h[bo]);
            wl[0][m] = *reinterpret_cast<const bf16x8*>(&w1l[bo]);
        }
        #pragma unroll
        for (int sl = 0; sl < 4; ++sl) {
            const int cur = sl & 1;
            if (sl < 3) {
                #pragma unroll
                for (int m = 0; m < 4; ++m) {
                    const size_t bo = ((size_t)((w * 4 + m) * 16 + ksg[sl + 1]) * 64 + l) * 8;
                    wh[cur ^ 1][m] = *reinterpret_cast<const bf16x8*>(&w1h[bo]);
                    wl[cur ^ 1][m] = *reinterpret_cast<const bf16x8*>(&w1l[bo]);
                }
            }
            #pragma unroll
            for (int nh = 0; nh < 2; ++nh) {
                bf16x8 fh[2];
                #pragma unroll
                for (int e = 0; e < 2; ++e)
                    fh[e] = *reinterpret_cast<const bf16x8*>(&buf[(sl * 4 + nh * 2 + e) * 512 + l * 8]);
                __builtin_amdgcn_s_setprio(1);
                #pragma unroll
                for (int m = 0; m < 4; ++m)
                    #pragma unroll
                    for (int e = 0; e < 2; ++e)
                        acc[m][nh * 2 + e] = __builtin_amdgcn_mfma_f32_16x16x32_bf16(wh[cur][m], fh[e], acc[m][nh * 2 + e], 0, 0, 0);
                #pragma unroll
                for (int m = 0; m < 4; ++m)
                    #pragma unroll
                    for (int e = 0; e < 2; ++e)
                        acc[m][nh * 2 + e] = __builtin_amdgcn_mfma_f32_16x16x32_bf16(wl[cur][m], fh[e], acc[m][nh * 2 + e], 0, 0, 0);
                __builtin_amdgcn_s_setprio(0);
            }
        }
    };

    // rebuild p = s~*d~, ad = |s~-d~| from bf16 s~,d~
    auto rebuild = [&](const u16* buf, float* pv, float* av) {
        const int bases[2] = {bS0, bS1};
        const int based[2] = {bD0, bD1};
        #pragma unroll
        for (int e = 0; e < 2; ++e) {
            u32x4 sh = *reinterpret_cast<const u32x4*>(&buf[bases[e]]);
            u32x4 dh = *reinterpret_cast<const u32x4*>(&buf[based[e]]);
            #pragma unroll
            for (int qq = 0; qq < 4; ++qq) {
                const float s0 = lo16f(sh[qq]);
                const float s1 = hi16f(sh[qq]);
                const float d0 = lo16f(dh[qq]);
                const float d1 = hi16f(dh[qq]);
                pv[e * 8 + 2 * qq]     = s0 * d0;
                pv[e * 8 + 2 * qq + 1] = s1 * d1;
                av[e * 8 + 2 * qq]     = fabsf(s0 - d0);
                av[e * 8 + 2 * qq + 1] = fabsf(s1 - d1);
            }
        }
    };

    // ---- seg0 compute + rebuild -> Bbuf ----
    run_pass(Abuf, 0, 1, 4, 5);
    {
        float pv[16], av[16];
        rebuild(Abuf, pv, av);
        store8(Bbuf, bS0, pv + 0);
        store8(Bbuf, bS1, pv + 8);
        store8(Bbuf, bD0, av + 0);
        store8(Bbuf, bD1, av + 8);
    }
    __syncthreads();   // bar2

    // ---- write held gather(ch64:128) -> Abuf, compute seg2 from Bbuf ----
    store8(Abuf, bS0, s1r + 0);
    store8(Abuf, bS1, s1r + 8);
    store8(Abuf, bD0, d1r + 0);
    store8(Abuf, bD1, d1r + 8);
    run_pass(Bbuf, 8, 9, 12, 13);
    __syncthreads();   // bar3

    // ---- seg1 compute + rebuild -> Bbuf ----
    run_pass(Abuf, 2, 3, 6, 7);
    {
        float pv[16], av[16];
        rebuild(Abuf, pv, av);
        store8(Bbuf, bS0, pv + 0);
        store8(Bbuf, bS1, pv + 8);
        store8(Bbuf, bD0, av + 0);
        store8(Bbuf, bD1, av + 8);
    }
    __syncthreads();   // bar4

    // ---- seg3 compute ----
    run_pass(Bbuf, 10, 11, 14, 15);

    // ---- layer 2 ----
    f32x4 acc2[2][4];
    #pragma unroll
    for (int m2 = 0; m2 < 2; ++m2)
        #pragma unroll
        for (int nt = 0; nt < 4; ++nt) acc2[m2][nt] = (f32x4){0.f, 0.f, 0.f, 0.f};

    auto epi1 = [&](u16* buf, int g) {
        #pragma unroll
        for (int mm = 0; mm < 2; ++mm) {
            const int m  = 2 * g + mm;
            const int mt = w * 4 + m;
            const int nb = mt * 16 + l4 * 4;
            float sb[4], wa[4], wb[4];
            *reinterpret_cast<float4*>(sb) = *reinterpret_cast<const float4*>(&Sb1[nb]);
            *reinterpret_cast<float4*>(wa) = *reinterpret_cast<const float4*>(&SW1[(size_t)512 * HID + nb]);
            *reinterpret_cast<float4*>(wb) = *reinterpret_cast<const float4*>(&SW1[(size_t)513 * HID + nb]);
            #pragma unroll
            for (int nt = 0; nt < 4; ++nt) {
                float v[4];
                #pragma unroll
                for (int r = 0; r < 4; ++r) {
                    float x0 = acc[m][nt][r] + sb[r];
                    x0 = fmaf(ldS[nt], wa[r], x0);
                    x0 = fmaf(ldD[nt], wb[r], x0);
                    v[r] = fmaxf(x0, 0.0f);
                }
                u32x2 hv;
                hv[0] = pk2(v[0], v[1]);
                hv[1] = pk2(v[2], v[3]);
                const int base = (w * 4 + nt) * 512
                               + (l15 + 16 * ((m & 1) * 2 + (l4 >> 1))) * 8
                               + (l4 & 1) * 4;
                *reinterpret_cast<u32x2*>(&buf[base]) = hv;
            }
        }
    };

    auto mfma2 = [&](const u16* buf, int g) {
        #pragma unroll
        for (int cs = 0; cs < 4; ++cs) {
            const int ks2 = cs * 2 + g;
            bf16x8 wh2[2], wl2[2];
            #pragma unroll
            for (int m2 = 0; m2 < 2; ++m2) {
                const size_t bo = ((size_t)((w * 2 + m2) * 8 + ks2) * 64 + l) * 8;
                wh2[m2] = *reinterpret_cast<const bf16x8*>(&w2h[bo]);
                wl2[m2] = *reinterpret_cast<const bf16x8*>(&w2l[bo]);
            }
            #pragma unroll
            for (int nh = 0; nh < 2; ++nh) {
                bf16x8 fh[2];
                #pragma unroll
                for (int e = 0; e < 2; ++e)
                    fh[e] = *reinterpret_cast<const bf16x8*>(&buf[(cs * 4 + nh * 2 + e) * 512 + l * 8]);
                __builtin_amdgcn_s_setprio(1);
                #pragma unroll
                for (int m2 = 0; m2 < 2; ++m2)
                    #pragma unroll
                    for (int e = 0; e < 2; ++e)
                        acc2[m2][nh * 2 + e] = __builtin_amdgcn_mfma_f32_16x16x32_bf16(wh2[m2], fh[e], acc2[m2][nh * 2 + e], 0, 0, 0);
                #pragma unroll
                for (int m2 = 0; m2 < 2; ++m2)
                    #pragma unroll
                    for (int e = 0; e < 2; ++e)
                        acc2[m2][nh * 2 + e] = __builtin_amdgcn_mfma_f32_16x16x32_bf16(wl2[m2], fh[e], acc2[m2][nh * 2 + e], 0, 0, 0);
                __builtin_amdgcn_s_setprio(0);
            }
        }
    };

    epi1(Abuf, 0);
    __syncthreads();         // bar5
    epi1(Bbuf, 1);           // overlaps mfma2(A)
    mfma2(Abuf, 0);
    __syncthreads();         // bar6
    mfma2(Bbuf, 1);

    // ---- epilogue 2 + layer 3 ----
    {
        float part[4] = {0.f, 0.f, 0.f, 0.f};
        #pragma unroll
        for (int m2 = 0; m2 < 2; ++m2) {
            const int nb2 = (w * 2 + m2) * 16 + l4 * 4;
            float sb[4], w3[4];
            *reinterpret_cast<float4*>(sb) = *reinterpret_cast<const float4*>(&Sb2[nb2]);
            *reinterpret_cast<float4*>(w3) = *reinterpret_cast<const float4*>(&SW3[nb2]);
            #pragma unroll
            for (int nt = 0; nt < 4; ++nt)
                #pragma unroll
                for (int r = 0; r < 4; ++r)
                    part[nt] = fmaf(fmaxf(acc2[m2][nt][r] + sb[r], 0.0f), w3[r], part[nt]);
        }
        #pragma unroll
        for (int nt = 0; nt < 4; ++nt) {
            part[nt] += __shfl_xor(part[nt], 16);
            part[nt] += __shfl_xor(part[nt], 32);
        }
        if (l < 16) {
            #pragma unroll
            for (int nt = 0; nt < 4; ++nt) red[w][nt][l15] = part[nt];
        }
    }
    __syncthreads();   // bar7

    if (t < 64) {
        const int nt = t >> 4, pp = t & 15;
        float v = red[0][nt][pp] + red[1][nt][pp] + red[2][nt][pp] + red[3][nt][pp] + Sb3[0];
        if (isnan(v)) v = 0.0f;
        else if (isinf(v)) v = (v > 0.0f) ? 20.0f : -20.0f;
        const int pidx = p0 + nt * 16 + pp;
        if (pidx < N_PAIRS) out[pidx] = v;
    }
}

// ---------------------------------------------------------------------------
extern "C" void kernel_launch(void* const* d_in, const int* in_sizes, int n_in,
                              void* d_out, int out_size, void* d_ws, size_t ws_size,
                              hipStream_t stream)
{
    const float* x        = (const float*)d_in[0];
    // d_in[1] = edge_index : unused by the reference
    const int*   pairs    = (const int*)d_in[2];
    const float* x_mean   = (const float*)d_in[3];
    const float* x_std    = (const float*)d_in[4];
    const float* logdeg   = (const float*)d_in[5];
    const float* W1       = (const float*)d_in[6];
    const float* b1       = (const float*)d_in[7];
    const float* bn_gamma = (const float*)d_in[8];
    const float* bn_beta  = (const float*)d_in[9];
    const float* bn_mean  = (const float*)d_in[10];
    const float* bn_var   = (const float*)d_in[11];
    const float* W2       = (const float*)d_in[12];
    const float* b2       = (const float*)d_in[13];
    const float* SW1      = (const float*)d_in[14];
    const float* Sb1      = (const float*)d_in[15];
    const float* SW2      = (const float*)d_in[16];
    const float* Sb2      = (const float*)d_in[17];
    const float* SW3      = (const float*)d_in[18];
    const float* Sb3      = (const float*)d_in[19];

    float* outp = (float*)d_out;

    // ws layout
    char* wsb = (char*)d_ws;
    float* zbuf = (float*)wsb;                          // 51,200,000 B
    u16* w1h  = (u16*)(wsb + 51200000);                 // 262144 B
    u16* w1l  = (u16*)(wsb + 51462144);                 // 262144 B
    u16* w2h  = (u16*)(wsb + 51724288);                 // 65536 B
    u16* w2l  = (u16*)(wsb + 51789824);                 // 65536 B
    u16* w1nh = (u16*)(wsb + 51855360);                 // 65536 B
    u16* w1nl = (u16*)(wsb + 51920896);                 // 65536 B
    u16* w2nh = (u16*)(wsb + 51986432);                 // 65536 B
    u16* w2nl = (u16*)(wsb + 52051968);                 // 65536 B  (end 52,117,504)

    prep_weights<<<896, 256, 0, stream>>>(SW1, SW2, W1, W2,
                                          w1h, w1l, w2h, w2l,
                                          w1nh, w1nl, w2nh, w2nl);

    node_mfma_kernel<<<(N_NODES + 63) / 64, 256, 0, stream>>>(
        x, x_mean, x_std, b1, bn_gamma, bn_beta, bn_mean, bn_var, b2,
        w1nh, w1nl, w2nh, w2nl, zbuf);

    pair_mfma_kernel<<<(N_PAIRS + PBM - 1) / PBM, 256, 0, stream>>>(
        zbuf, pairs, logdeg, w1h, w1l, w2h, w2l, SW1, Sb1, Sb2, SW3, Sb3, outp);
}

// Round 12
// 352.397 us; speedup vs baseline: 1.8407x; 1.0953x over previous
//
#include <hip/hip_runtime.h>
#include <hip/hip_bf16.h>
#include <math.h>

typedef unsigned short u16;
typedef __attribute__((ext_vector_type(8))) short bf16x8;
typedef __attribute__((ext_vector_type(8))) unsigned short u16x8;
typedef __attribute__((ext_vector_type(4))) float f32x4;
typedef __attribute__((ext_vector_type(4))) unsigned u32x4;
typedef __attribute__((ext_vector_type(2))) unsigned u32x2;

#define N_NODES 100000
#define IN_CH 128
#define HID 256
#define EMB 128
#define N_PAIRS 500000
#define BN_EPS 1e-5f

#define PBM 64  // pairs per block (kernel B); 64 nodes/block (kernel A)

// ---- bf16 helpers ----
__device__ __forceinline__ u16 f2bf(float f) {            // scalar RNE (prep kernel)
    unsigned u = __builtin_bit_cast(unsigned, f);
    unsigned r = u + 0x7FFFu + ((u >> 16) & 1u);
    return (u16)(r >> 16);
}
__device__ __forceinline__ float bf2f(u16 h) {
    unsigned u = ((unsigned)h) << 16;
    return __builtin_bit_cast(float, u);
}
// packed pair conversion -> v_cvt_pk_bf16_f32
__device__ __forceinline__ unsigned pk2(float a, float b) {
    __hip_bfloat162 h = __float22bfloat162_rn(make_float2(a, b));
    unsigned u;
    __builtin_memcpy(&u, &h, sizeof(u));
    return u;
}
__device__ __forceinline__ float lo16f(unsigned u) { return __builtin_bit_cast(float, u << 16); }
__device__ __forceinline__ float hi16f(unsigned u) { return __builtin_bit_cast(float, u & 0xffff0000u); }

// store 8 floats as bf16 at u16-index base
__device__ __forceinline__ void store8(u16* buf, int base, const float* v) {
    u32x4 hv;
    #pragma unroll
    for (int q = 0; q < 4; ++q) hv[q] = pk2(v[2 * q], v[2 * q + 1]);
    *reinterpret_cast<u32x4*>(&buf[base]) = hv;
}

// ---------------------------------------------------------------------------
// Weight prep into MFMA A-operand fragment-linear layout (weights on M-side):
// idx = ((mt*KS + ks)*64 + l)*8 + j ; value = W[k][n], n = mt*16 + (l&15),
// k = ks*32 + (l>>4)*8 + j. Covers SW1 (16x16), SW2 (8x8), W1 (16x4), W2 (8x8).
// ---------------------------------------------------------------------------
__global__ __launch_bounds__(256) void prep_weights(
    const float* __restrict__ SW1, const float* __restrict__ SW2,
    const float* __restrict__ W1,  const float* __restrict__ W2,
    u16* __restrict__ w1h, u16* __restrict__ w1l,
    u16* __restrict__ w2h, u16* __restrict__ w2l,
    u16* __restrict__ w1nh, u16* __restrict__ w1nl,
    u16* __restrict__ w2nh, u16* __restrict__ w2nl)
{
    const int tid = blockIdx.x * 256 + threadIdx.x;
    if (tid < 131072) {                       // SW1 frags: 16 mt x 16 ks
        const int j = tid & 7, l = (tid >> 3) & 63, ks = (tid >> 9) & 15, mt = tid >> 13;
        const int n = mt * 16 + (l & 15);
        const int k = ks * 32 + ((l >> 4) << 3) + j;
        const float v = SW1[(size_t)k * HID + n];
        const u16 h = f2bf(v);
        w1h[tid] = h;
        w1l[tid] = f2bf(v - bf2f(h));
    } else if (tid < 163840) {                // SW2 frags: 8 mt x 8 ks
        const int t2 = tid - 131072;
        const int j = t2 & 7, l = (t2 >> 3) & 63, ks = (t2 >> 9) & 7, mt = t2 >> 12;
        const int n = mt * 16 + (l & 15);
        const int k = ks * 32 + ((l >> 4) << 3) + j;
        const float v = SW2[(size_t)k * (HID / 2) + n];
        const u16 h = f2bf(v);
        w2h[t2] = h;
        w2l[t2] = f2bf(v - bf2f(h));
    } else if (tid < 196608) {                // W1 node frags: 16 mt x 4 ks
        const int t3 = tid - 163840;
        const int j = t3 & 7, l = (t3 >> 3) & 63, ks = (t3 >> 9) & 3, mt = t3 >> 11;
        const int n = mt * 16 + (l & 15);
        const int k = ks * 32 + ((l >> 4) << 3) + j;
        const float v = W1[(size_t)k * HID + n];
        const u16 h = f2bf(v);
        w1nh[t3] = h;
        w1nl[t3] = f2bf(v - bf2f(h));
    } else if (tid < 229376) {                // W2 node frags: 8 mt x 8 ks
        const int t4 = tid - 196608;
        const int j = t4 & 7, l = (t4 >> 3) & 63, ks = (t4 >> 9) & 7, mt = t4 >> 12;
        const int n = mt * 16 + (l & 15);
        const int k = ks * 32 + ((l >> 4) << 3) + j;
        const float v = W2[(size_t)k * EMB + n];
        const u16 h = f2bf(v);
        w2nh[t4] = h;
        w2nl[t4] = f2bf(v - bf2f(h));
    }
}

// ---------------------------------------------------------------------------
// Kernel A (MFMA): node MLP. 64 nodes/block, 4 waves. Output z in BF16
// (bit-identical to bf16(relu(...)) since features only use bf16(z)).
// ---------------------------------------------------------------------------
__global__ __launch_bounds__(256) void node_mfma_kernel(
    const float* __restrict__ x,
    const float* __restrict__ x_mean, const float* __restrict__ x_std,
    const float* __restrict__ b1,
    const float* __restrict__ bn_gamma, const float* __restrict__ bn_beta,
    const float* __restrict__ bn_mean,  const float* __restrict__ bn_var,
    const float* __restrict__ b2,
    const u16* __restrict__ w1nh, const u16* __restrict__ w1nl,
    const u16* __restrict__ w2nh, const u16* __restrict__ w2nl,
    u16* __restrict__ z)
{
    __shared__ __align__(16) u16 XF[8192];    // 16 KB: [slot 0..3][nt 0..3][512]
    __shared__ __align__(16) u16 HF[16384];   // 32 KB: [ks2 0..7][nt 0..3][512]

    const int t   = threadIdx.x;
    const int w   = t >> 6;
    const int l   = t & 63;
    const int l15 = l & 15;
    const int l4  = l >> 4;
    const int n0  = blockIdx.x * 64;
    const int nd  = (n0 + l < N_NODES) ? (n0 + l) : (N_NODES - 1);

    // ---- stage xf: thread (w,l) = node l, channels [w*32, w*32+32) ----
    {
        const float* xp = x + (size_t)nd * IN_CH + w * 32;
        float v[32];
        #pragma unroll
        for (int q = 0; q < 8; ++q)
            *reinterpret_cast<float4*>(&v[q * 4]) = *reinterpret_cast<const float4*>(xp + q * 4);
        #pragma unroll
        for (int q = 0; q < 8; ++q) {
            float4 m4 = *reinterpret_cast<const float4*>(x_mean + w * 32 + q * 4);
            float4 s4 = *reinterpret_cast<const float4*>(x_std  + w * 32 + q * 4);
            float mm[4] = {m4.x, m4.y, m4.z, m4.w};
            float ss[4] = {s4.x, s4.y, s4.z, s4.w};
            #pragma unroll
            for (int e = 0; e < 4; ++e) {
                float val = v[q * 4 + e];
                if (!isfinite(val)) val = 0.0f;
                val = (val - mm[e]) / ss[e];
                v[q * 4 + e] = fminf(fmaxf(val, -10.0f), 10.0f);
            }
        }
        #pragma unroll
        for (int q = 0; q < 4; ++q) {
            const int base = (w * 4 + l4) * 512 + (l15 + 16 * q) * 8;
            store8(XF, base, &v[q * 8]);
        }
    }
    __syncthreads();

    // ---- L1: acc[m][nt], wave owns mt {4w..4w+3}, K=128 ----
    f32x4 acc[4][4];
    #pragma unroll
    for (int m = 0; m < 4; ++m)
        #pragma unroll
        for (int nt = 0; nt < 4; ++nt) acc[m][nt] = (f32x4){0.f, 0.f, 0.f, 0.f};

    #pragma unroll
    for (int sl = 0; sl < 4; ++sl) {
        bf16x8 wh[4], wl[4];
        #pragma unroll
        for (int m = 0; m < 4; ++m) {
            const size_t bo = ((size_t)((w * 4 + m) * 4 + sl) * 64 + l) * 8;
            wh[m] = *reinterpret_cast<const bf16x8*>(&w1nh[bo]);
            wl[m] = *reinterpret_cast<const bf16x8*>(&w1nl[bo]);
        }
        bf16x8 fh[4];
        #pragma unroll
        for (int nt = 0; nt < 4; ++nt)
            fh[nt] = *reinterpret_cast<const bf16x8*>(&XF[(sl * 4 + nt) * 512 + l * 8]);
        __builtin_amdgcn_s_setprio(1);
        #pragma unroll
        for (int m = 0; m < 4; ++m)
            #pragma unroll
            for (int nt = 0; nt < 4; ++nt)
                acc[m][nt] = __builtin_amdgcn_mfma_f32_16x16x32_bf16(wh[m], fh[nt], acc[m][nt], 0, 0, 0);
        #pragma unroll
        for (int m = 0; m < 4; ++m)
            #pragma unroll
            for (int nt = 0; nt < 4; ++nt)
                acc[m][nt] = __builtin_amdgcn_mfma_f32_16x16x32_bf16(wl[m], fh[nt], acc[m][nt], 0, 0, 0);
        __builtin_amdgcn_s_setprio(0);
    }

    // ---- epilogue 1: BN + relu -> HF (bf16) ----
    #pragma unroll
    for (int m = 0; m < 4; ++m) {
        const int mt = w * 4 + m;
        const int nb = mt * 16 + l4 * 4;
        float4 b1v = *reinterpret_cast<const float4*>(b1 + nb);
        float4 gv  = *reinterpret_cast<const float4*>(bn_gamma + nb);
        float4 bev = *reinterpret_cast<const float4*>(bn_beta + nb);
        float4 mev = *reinterpret_cast<const float4*>(bn_mean + nb);
        float4 vav = *reinterpret_cast<const float4*>(bn_var + nb);
        float scale[4], shift[4];
        float bb[4] = {b1v.x, b1v.y, b1v.z, b1v.w};
        float gg[4] = {gv.x, gv.y, gv.z, gv.w};
        float be[4] = {bev.x, bev.y, bev.z, bev.w};
        float me[4] = {mev.x, mev.y, mev.z, mev.w};
        float va[4] = {vav.x, vav.y, vav.z, vav.w};
        #pragma unroll
        for (int r = 0; r < 4; ++r) {
            scale[r] = gg[r] * rsqrtf(va[r] + BN_EPS);
            shift[r] = (bb[r] - me[r]) * scale[r] + be[r];
        }
        #pragma unroll
        for (int nt = 0; nt < 4; ++nt) {
            float v[4];
            #pragma unroll
            for (int r = 0; r < 4; ++r)
                v[r] = fmaxf(fmaf(acc[m][nt][r], scale[r], shift[r]), 0.0f);
            u32x2 hv;
            hv[0] = pk2(v[0], v[1]);
            hv[1] = pk2(v[2], v[3]);
            const int base = ((mt >> 1) * 4 + nt) * 512
                           + (l15 + 16 * ((mt & 1) * 2 + (l4 >> 1))) * 8
                           + (l4 & 1) * 4;
            *reinterpret_cast<u32x2*>(&HF[base]) = hv;
        }
    }
    __syncthreads();

    // ---- L2: acc2[m2][nt], wave owns mt2 {2w, 2w+1}, K=256 ----
    f32x4 acc2[2][4];
    #pragma unroll
    for (int m2 = 0; m2 < 2; ++m2)
        #pragma unroll
        for (int nt = 0; nt < 4; ++nt) acc2[m2][nt] = (f32x4){0.f, 0.f, 0.f, 0.f};

    #pragma unroll
    for (int ks2 = 0; ks2 < 8; ++ks2) {
        bf16x8 wh2[2], wl2[2];
        #pragma unroll
        for (int m2 = 0; m2 < 2; ++m2) {
            const size_t bo = ((size_t)((w * 2 + m2) * 8 + ks2) * 64 + l) * 8;
            wh2[m2] = *reinterpret_cast<const bf16x8*>(&w2nh[bo]);
            wl2[m2] = *reinterpret_cast<const bf16x8*>(&w2nl[bo]);
        }
        bf16x8 fh[4];
        #pragma unroll
        for (int nt = 0; nt < 4; ++nt)
            fh[nt] = *reinterpret_cast<const bf16x8*>(&HF[(ks2 * 4 + nt) * 512 + l * 8]);
        __builtin_amdgcn_s_setprio(1);
        #pragma unroll
        for (int m2 = 0; m2 < 2; ++m2)
            #pragma unroll
            for (int nt = 0; nt < 4; ++nt)
                acc2[m2][nt] = __builtin_amdgcn_mfma_f32_16x16x32_bf16(wh2[m2], fh[nt], acc2[m2][nt], 0, 0, 0);
        #pragma unroll
        for (int m2 = 0; m2 < 2; ++m2)
            #pragma unroll
            for (int nt = 0; nt < 4; ++nt)
                acc2[m2][nt] = __builtin_amdgcn_mfma_f32_16x16x32_bf16(wl2[m2], fh[nt], acc2[m2][nt], 0, 0, 0);
        __builtin_amdgcn_s_setprio(0);
    }

    // ---- epilogue 2: z = bf16(relu(acc2 + b2)) -> global ----
    #pragma unroll
    for (int m2 = 0; m2 < 2; ++m2) {
        const int nb2 = (w * 2 + m2) * 16 + l4 * 4;
        float4 b2v = *reinterpret_cast<const float4*>(b2 + nb2);
        float bb[4] = {b2v.x, b2v.y, b2v.z, b2v.w};
        #pragma unroll
        for (int nt = 0; nt < 4; ++nt) {
            const int node = n0 + nt * 16 + l15;
            if (node < N_NODES) {
                float v0 = fmaxf(acc2[m2][nt][0] + bb[0], 0.0f);
                float v1 = fmaxf(acc2[m2][nt][1] + bb[1], 0.0f);
                float v2 = fmaxf(acc2[m2][nt][2] + bb[2], 0.0f);
                float v3 = fmaxf(acc2[m2][nt][3] + bb[3], 0.0f);
                u32x2 hv;
                hv[0] = pk2(v0, v1);
                hv[1] = pk2(v2, v3);
                *reinterpret_cast<u32x2*>(z + (size_t)node * EMB + nb2) = hv;
            }
        }
    }
}

// ---------------------------------------------------------------------------
// Kernel B (MFMA): 64 pairs/block, 4 waves, r11 schedule, 2-product split.
// z is BF16: phase-0 staging is raw u16x8 copies (no conversion), rebuild
// uses the held gather registers (no LDS read-back).
// ---------------------------------------------------------------------------
__global__ __launch_bounds__(256) void pair_mfma_kernel(
    const u16* __restrict__ z,
    const int* __restrict__ pairs,
    const float* __restrict__ logdeg,
    const u16* __restrict__ w1h, const u16* __restrict__ w1l,
    const u16* __restrict__ w2h, const u16* __restrict__ w2l,
    const float* __restrict__ SW1, const float* __restrict__ Sb1,
    const float* __restrict__ Sb2,
    const float* __restrict__ SW3, const float* __restrict__ Sb3,
    float* __restrict__ out)
{
    __shared__ __align__(16) u16 Abuf[8192];   // 16 KB
    __shared__ __align__(16) u16 Bbuf[8192];   // 16 KB
    __shared__ float red[4][4][16];            // 1 KB

    const int t   = threadIdx.x;
    const int w   = t >> 6;        // wave 0..3
    const int l   = t & 63;
    const int l15 = l & 15;
    const int l4  = l >> 4;
    const int p0  = blockIdx.x * PBM;

    // thread (w,l): pair l, channels [w*16, w*16+16) of a 64-ch half.
    const int qb  = (w & 1) * 2;
    const int bS0 = (((w >> 1)) * 4 + l4) * 512 + (l15 + 16 * (qb + 0)) * 8;
    const int bS1 = (((w >> 1)) * 4 + l4) * 512 + (l15 + 16 * (qb + 1)) * 8;
    const int bD0 = ((2 + (w >> 1)) * 4 + l4) * 512 + (l15 + 16 * (qb + 0)) * 8;
    const int bD1 = ((2 + (w >> 1)) * 4 + l4) * 512 + (l15 + 16 * (qb + 1)) * 8;

    const int gp  = (p0 + l < N_PAIRS) ? (p0 + l) : (N_PAIRS - 1);
    const int gsi = pairs[(size_t)gp * 2 + 0];
    const int gdi = pairs[(size_t)gp * 2 + 1];

    // ---- gather both halves (bf16, raw u16x8), stage half-0 -> Abuf ----
    const u16* zs0 = z + (size_t)gsi * EMB + w * 16;
    const u16* zd0 = z + (size_t)gdi * EMB + w * 16;
    u16x8 s00 = *reinterpret_cast<const u16x8*>(zs0);
    u16x8 s01 = *reinterpret_cast<const u16x8*>(zs0 + 8);
    u16x8 d00 = *reinterpret_cast<const u16x8*>(zd0);
    u16x8 d01 = *reinterpret_cast<const u16x8*>(zd0 + 8);
    u16x8 s10 = *reinterpret_cast<const u16x8*>(zs0 + 64);
    u16x8 s11 = *reinterpret_cast<const u16x8*>(zs0 + 72);
    u16x8 d10 = *reinterpret_cast<const u16x8*>(zd0 + 64);
    u16x8 d11 = *reinterpret_cast<const u16x8*>(zd0 + 72);

    *reinterpret_cast<u16x8*>(&Abuf[bS0]) = s00;
    *reinterpret_cast<u16x8*>(&Abuf[bS1]) = s01;
    *reinterpret_cast<u16x8*>(&Abuf[bD0]) = d00;
    *reinterpret_cast<u16x8*>(&Abuf[bD1]) = d01;

    // ---- prefetch epilogue-1 gather data ----
    float ldS[4], ldD[4];
    #pragma unroll
    for (int nt = 0; nt < 4; ++nt) {
        const int pidx = (p0 + nt * 16 + l15 < N_PAIRS) ? (p0 + nt * 16 + l15) : (N_PAIRS - 1);
        ldS[nt] = logdeg[pairs[(size_t)pidx * 2 + 0]];
        ldD[nt] = logdeg[pairs[(size_t)pidx * 2 + 1]];
    }

    __syncthreads();   // bar1

    f32x4 acc[4][4];
    #pragma unroll
    for (int m = 0; m < 4; ++m)
        #pragma unroll
        for (int nt = 0; nt < 4; ++nt) acc[m][nt] = (f32x4){0.f, 0.f, 0.f, 0.f};

    // one 128-K segment; weight register dbuf across sl; 2-product
    auto run_pass = [&](const u16* buf, int k0, int k1, int k2, int k3) {
        const int ksg[4] = {k0, k1, k2, k3};
        bf16x8 wh[2][4], wl[2][4];
        #pragma unroll
        for (int m = 0; m < 4; ++m) {
            const size_t bo = ((size_t)((w * 4 + m) * 16 + ksg[0]) * 64 + l) * 8;
            wh[0][m] = *reinterpret_cast<const bf16x8*>(&w1h[bo]);
            wl[0][m] = *reinterpret_cast<const bf16x8*>(&w1l[bo]);
        }
        #pragma unroll
        for (int sl = 0; sl < 4; ++sl) {
            const int cur = sl & 1;
            if (sl < 3) {
                #pragma unroll
                for (int m = 0; m < 4; ++m) {
                    const size_t bo = ((size_t)((w * 4 + m) * 16 + ksg[sl + 1]) * 64 + l) * 8;
                    wh[cur ^ 1][m] = *reinterpret_cast<const bf16x8*>(&w1h[bo]);
                    wl[cur ^ 1][m] = *reinterpret_cast<const bf16x8*>(&w1l[bo]);
                }
            }
            #pragma unroll
            for (int nh = 0; nh < 2; ++nh) {
                bf16x8 fh[2];
                #pragma unroll
                for (int e = 0; e < 2; ++e)
                    fh[e] = *reinterpret_cast<const bf16x8*>(&buf[(sl * 4 + nh * 2 + e) * 512 + l * 8]);
                __builtin_amdgcn_s_setprio(1);
                #pragma unroll
                for (int m = 0; m < 4; ++m)
                    #pragma unroll
                    for (int e = 0; e < 2; ++e)
                        acc[m][nh * 2 + e] = __builtin_amdgcn_mfma_f32_16x16x32_bf16(wh[cur][m], fh[e], acc[m][nh * 2 + e], 0, 0, 0);
                #pragma unroll
                for (int m = 0; m < 4; ++m)
                    #pragma unroll
                    for (int e = 0; e < 2; ++e)
                        acc[m][nh * 2 + e] = __builtin_amdgcn_mfma_f32_16x16x32_bf16(wl[cur][m], fh[e], acc[m][nh * 2 + e], 0, 0, 0);
                __builtin_amdgcn_s_setprio(0);
            }
        }
    };

    // rebuild p = s~*d~, ad = |s~-d~| from HELD registers (z already bf16)
    auto rebuildR = [&](u16x8 sa, u16x8 sb, u16x8 da, u16x8 db, float* pv, float* av) {
        #pragma unroll
        for (int qq = 0; qq < 8; ++qq) {
            const float s = bf2f(sa[qq]);
            const float d = bf2f(da[qq]);
            pv[qq] = s * d;
            av[qq] = fabsf(s - d);
        }
        #pragma unroll
        for (int qq = 0; qq < 8; ++qq) {
            const float s = bf2f(sb[qq]);
            const float d = bf2f(db[qq]);
            pv[8 + qq] = s * d;
            av[8 + qq] = fabsf(s - d);
        }
    };

    // ---- seg0 compute + rebuild(half-0 regs) -> Bbuf ----
    run_pass(Abuf, 0, 1, 4, 5);
    {
        float pv[16], av[16];
        rebuildR(s00, s01, d00, d01, pv, av);
        store8(Bbuf, bS0, pv + 0);
        store8(Bbuf, bS1, pv + 8);
        store8(Bbuf, bD0, av + 0);
        store8(Bbuf, bD1, av + 8);
    }
    __syncthreads();   // bar2: Bbuf visible; all Abuf reads retired

    // ---- write held half-1 -> Abuf, compute seg2 from Bbuf ----
    *reinterpret_cast<u16x8*>(&Abuf[bS0]) = s10;
    *reinterpret_cast<u16x8*>(&Abuf[bS1]) = s11;
    *reinterpret_cast<u16x8*>(&Abuf[bD0]) = d10;
    *reinterpret_cast<u16x8*>(&Abuf[bD1]) = d11;
    run_pass(Bbuf, 8, 9, 12, 13);
    __syncthreads();   // bar3

    // ---- seg1 compute + rebuild(half-1 regs) -> Bbuf ----
    run_pass(Abuf, 2, 3, 6, 7);
    {
        float pv[16], av[16];
        rebuildR(s10, s11, d10, d11, pv, av);
        store8(Bbuf, bS0, pv + 0);
        store8(Bbuf, bS1, pv + 8);
        store8(Bbuf, bD0, av + 0);
        store8(Bbuf, bD1, av + 8);
    }
    __syncthreads();   // bar4

    // ---- seg3 compute ----
    run_pass(Bbuf, 10, 11, 14, 15);

    // ---- layer 2 ----
    f32x4 acc2[2][4];
    #pragma unroll
    for (int m2 = 0; m2 < 2; ++m2)
        #pragma unroll
        for (int nt = 0; nt < 4; ++nt) acc2[m2][nt] = (f32x4){0.f, 0.f, 0.f, 0.f};

    auto epi1 = [&](u16* buf, int g) {
        #pragma unroll
        for (int mm = 0; mm < 2; ++mm) {
            const int m  = 2 * g + mm;
            const int mt = w * 4 + m;
            const int nb = mt * 16 + l4 * 4;
            float sb[4], wa[4], wb[4];
            *reinterpret_cast<float4*>(sb) = *reinterpret_cast<const float4*>(&Sb1[nb]);
            *reinterpret_cast<float4*>(wa) = *reinterpret_cast<const float4*>(&SW1[(size_t)512 * HID + nb]);
            *reinterpret_cast<float4*>(wb) = *reinterpret_cast<const float4*>(&SW1[(size_t)513 * HID + nb]);
            #pragma unroll
            for (int nt = 0; nt < 4; ++nt) {
                float v[4];
                #pragma unroll
                for (int r = 0; r < 4; ++r) {
                    float x0 = acc[m][nt][r] + sb[r];
                    x0 = fmaf(ldS[nt], wa[r], x0);
                    x0 = fmaf(ldD[nt], wb[r], x0);
                    v[r] = fmaxf(x0, 0.0f);
                }
                u32x2 hv;
                hv[0] = pk2(v[0], v[1]);
                hv[1] = pk2(v[2], v[3]);
                const int base = (w * 4 + nt) * 512
                               + (l15 + 16 * ((m & 1) * 2 + (l4 >> 1))) * 8
                               + (l4 & 1) * 4;
                *reinterpret_cast<u32x2*>(&buf[base]) = hv;
            }
        }
    };

    auto mfma2 = [&](const u16* buf, int g) {
        #pragma unroll
        for (int cs = 0; cs < 4; ++cs) {
            const int ks2 = cs * 2 + g;
            bf16x8 wh2[2], wl2[2];
            #pragma unroll
            for (int m2 = 0; m2 < 2; ++m2) {
                const size_t bo = ((size_t)((w * 2 + m2) * 8 + ks2) * 64 + l) * 8;
                wh2[m2] = *reinterpret_cast<const bf16x8*>(&w2h[bo]);
                wl2[m2] = *reinterpret_cast<const bf16x8*>(&w2l[bo]);
            }
            #pragma unroll
            for (int nh = 0; nh < 2; ++nh) {
                bf16x8 fh[2];
                #pragma unroll
                for (int e = 0; e < 2; ++e)
                    fh[e] = *reinterpret_cast<const bf16x8*>(&buf[(cs * 4 + nh * 2 + e) * 512 + l * 8]);
                __builtin_amdgcn_s_setprio(1);
                #pragma unroll
                for (int m2 = 0; m2 < 2; ++m2)
                    #pragma unroll
                    for (int e = 0; e < 2; ++e)
                        acc2[m2][nh * 2 + e] = __builtin_amdgcn_mfma_f32_16x16x32_bf16(wh2[m2], fh[e], acc2[m2][nh * 2 + e], 0, 0, 0);
                #pragma unroll
                for (int m2 = 0; m2 < 2; ++m2)
                    #pragma unroll
                    for (int e = 0; e < 2; ++e)
                        acc2[m2][nh * 2 + e] = __builtin_amdgcn_mfma_f32_16x16x32_bf16(wl2[m2], fh[e], acc2[m2][nh * 2 + e], 0, 0, 0);
                __builtin_amdgcn_s_setprio(0);
            }
        }
    };

    epi1(Abuf, 0);
    __syncthreads();         // bar5
    epi1(Bbuf, 1);           // overlaps mfma2(A)
    mfma2(Abuf, 0);
    __syncthreads();         // bar6
    mfma2(Bbuf, 1);

    // ---- epilogue 2 + layer 3 ----
    {
        float part[4] = {0.f, 0.f, 0.f, 0.f};
        #pragma unroll
        for (int m2 = 0; m2 < 2; ++m2) {
            const int nb2 = (w * 2 + m2) * 16 + l4 * 4;
            float sb[4], w3[4];
            *reinterpret_cast<float4*>(sb) = *reinterpret_cast<const float4*>(&Sb2[nb2]);
            *reinterpret_cast<float4*>(w3) = *reinterpret_cast<const float4*>(&SW3[nb2]);
            #pragma unroll
            for (int nt = 0; nt < 4; ++nt)
                #pragma unroll
                for (int r = 0; r < 4; ++r)
                    part[nt] = fmaf(fmaxf(acc2[m2][nt][r] + sb[r], 0.0f), w3[r], part[nt]);
        }
        #pragma unroll
        for (int nt = 0; nt < 4; ++nt) {
            part[nt] += __shfl_xor(part[nt], 16);
            part[nt] += __shfl_xor(part[nt], 32);
        }
        if (l < 16) {
            #pragma unroll
            for (int nt = 0; nt < 4; ++nt) red[w][nt][l15] = part[nt];
        }
    }
    __syncthreads();   // bar7

    if (t < 64) {
        const int nt = t >> 4, pp = t & 15;
        float v = red[0][nt][pp] + red[1][nt][pp] + red[2][nt][pp] + red[3][nt][pp] + Sb3[0];
        if (isnan(v)) v = 0.0f;
        else if (isinf(v)) v = (v > 0.0f) ? 20.0f : -20.0f;
        const int pidx = p0 + nt * 16 + pp;
        if (pidx < N_PAIRS) out[pidx] = v;
    }
}

// ---------------------------------------------------------------------------
extern "C" void kernel_launch(void* const* d_in, const int* in_sizes, int n_in,
                              void* d_out, int out_size, void* d_ws, size_t ws_size,
                              hipStream_t stream)
{
    const float* x        = (const float*)d_in[0];
    // d_in[1] = edge_index : unused by the reference
    const int*   pairs    = (const int*)d_in[2];
    const float* x_mean   = (const float*)d_in[3];
    const float* x_std    = (const float*)d_in[4];
    const float* logdeg   = (const float*)d_in[5];
    const float* W1       = (const float*)d_in[6];
    const float* b1       = (const float*)d_in[7];
    const float* bn_gamma = (const float*)d_in[8];
    const float* bn_beta  = (const float*)d_in[9];
    const float* bn_mean  = (const float*)d_in[10];
    const float* bn_var   = (const float*)d_in[11];
    const float* W2       = (const float*)d_in[12];
    const float* b2       = (const float*)d_in[13];
    const float* SW1      = (const float*)d_in[14];
    const float* Sb1      = (const float*)d_in[15];
    const float* SW2      = (const float*)d_in[16];
    const float* Sb2      = (const float*)d_in[17];
    const float* SW3      = (const float*)d_in[18];
    const float* Sb3      = (const float*)d_in[19];

    float* outp = (float*)d_out;

    // ws layout (z now bf16: 100000*128*2 = 25,600,000 B)
    char* wsb = (char*)d_ws;
    u16* zbuf = (u16*)wsb;
    u16* w1h  = (u16*)(wsb + 25600000);                 // 262144 B
    u16* w1l  = (u16*)(wsb + 25862144);                 // 262144 B
    u16* w2h  = (u16*)(wsb + 26124288);                 // 65536 B
    u16* w2l  = (u16*)(wsb + 26189824);                 // 65536 B
    u16* w1nh = (u16*)(wsb + 26255360);                 // 65536 B
    u16* w1nl = (u16*)(wsb + 26320896);                 // 65536 B
    u16* w2nh = (u16*)(wsb + 26386432);                 // 65536 B
    u16* w2nl = (u16*)(wsb + 26451968);                 // 65536 B (end 26,517,504)

    prep_weights<<<896, 256, 0, stream>>>(SW1, SW2, W1, W2,
                                          w1h, w1l, w2h, w2l,
                                          w1nh, w1nl, w2nh, w2nl);

    node_mfma_kernel<<<(N_NODES + 63) / 64, 256, 0, stream>>>(
        x, x_mean, x_std, b1, bn_gamma, bn_beta, bn_mean, bn_var, b2,
        w1nh, w1nl, w2nh, w2nl, zbuf);

    pair_mfma_kernel<<<(N_PAIRS + PBM - 1) / PBM, 256, 0, stream>>>(
        zbuf, pairs, logdeg, w1h, w1l, w2h, w2l, SW1, Sb1, Sb2, SW3, Sb3, outp);
}

// Round 13
// 256.250 us; speedup vs baseline: 2.5313x; 1.3752x over previous
//
#include <hip/hip_runtime.h>
#include <hip/hip_bf16.h>
#include <math.h>

typedef unsigned short u16;
typedef __attribute__((ext_vector_type(8))) short bf16x8;
typedef __attribute__((ext_vector_type(8))) unsigned short u16x8;
typedef __attribute__((ext_vector_type(4))) float f32x4;
typedef __attribute__((ext_vector_type(4))) unsigned u32x4;
typedef __attribute__((ext_vector_type(2))) unsigned u32x2;

#define N_NODES 100000
#define IN_CH 128
#define HID 256
#define EMB 128
#define N_PAIRS 500000
#define BN_EPS 1e-5f

#define PBM 64  // pairs per block (kernel B); 64 nodes/block (kernel A)

// ---- bf16 helpers ----
__device__ __forceinline__ u16 f2bf(float f) {            // scalar RNE (prep kernel)
    unsigned u = __builtin_bit_cast(unsigned, f);
    unsigned r = u + 0x7FFFu + ((u >> 16) & 1u);
    return (u16)(r >> 16);
}
__device__ __forceinline__ float bf2f(u16 h) {
    unsigned u = ((unsigned)h) << 16;
    return __builtin_bit_cast(float, u);
}
// packed pair conversion -> v_cvt_pk_bf16_f32
__device__ __forceinline__ unsigned pk2(float a, float b) {
    __hip_bfloat162 h = __float22bfloat162_rn(make_float2(a, b));
    unsigned u;
    __builtin_memcpy(&u, &h, sizeof(u));
    return u;
}
__device__ __forceinline__ float lo16f(unsigned u) { return __builtin_bit_cast(float, u << 16); }
__device__ __forceinline__ float hi16f(unsigned u) { return __builtin_bit_cast(float, u & 0xffff0000u); }

// store 8 floats as bf16 at u16-index base
__device__ __forceinline__ void store8(u16* buf, int base, const float* v) {
    u32x4 hv;
    #pragma unroll
    for (int q = 0; q < 4; ++q) hv[q] = pk2(v[2 * q], v[2 * q + 1]);
    *reinterpret_cast<u32x4*>(&buf[base]) = hv;
}

// ---------------------------------------------------------------------------
// Weight prep into MFMA A-operand fragment-linear layout (weights on M-side):
// idx = ((mt*KS + ks)*64 + l)*8 + j ; value = W[k][n], n = mt*16 + (l&15),
// k = ks*32 + (l>>4)*8 + j. SW1/SW2 hi-only (1-product pair kernel);
// W1/W2 node weights keep hi+lo (2-product, z kept accurate).
// ---------------------------------------------------------------------------
__global__ __launch_bounds__(256) void prep_weights(
    const float* __restrict__ SW1, const float* __restrict__ SW2,
    const float* __restrict__ W1,  const float* __restrict__ W2,
    u16* __restrict__ w1h, u16* __restrict__ w2h,
    u16* __restrict__ w1nh, u16* __restrict__ w1nl,
    u16* __restrict__ w2nh, u16* __restrict__ w2nl)
{
    const int tid = blockIdx.x * 256 + threadIdx.x;
    if (tid < 131072) {                       // SW1 frags: 16 mt x 16 ks
        const int j = tid & 7, l = (tid >> 3) & 63, ks = (tid >> 9) & 15, mt = tid >> 13;
        const int n = mt * 16 + (l & 15);
        const int k = ks * 32 + ((l >> 4) << 3) + j;
        w1h[tid] = f2bf(SW1[(size_t)k * HID + n]);
    } else if (tid < 163840) {                // SW2 frags: 8 mt x 8 ks
        const int t2 = tid - 131072;
        const int j = t2 & 7, l = (t2 >> 3) & 63, ks = (t2 >> 9) & 7, mt = t2 >> 12;
        const int n = mt * 16 + (l & 15);
        const int k = ks * 32 + ((l >> 4) << 3) + j;
        w2h[t2] = f2bf(SW2[(size_t)k * (HID / 2) + n]);
    } else if (tid < 196608) {                // W1 node frags: 16 mt x 4 ks
        const int t3 = tid - 163840;
        const int j = t3 & 7, l = (t3 >> 3) & 63, ks = (t3 >> 9) & 3, mt = t3 >> 11;
        const int n = mt * 16 + (l & 15);
        const int k = ks * 32 + ((l >> 4) << 3) + j;
        const float v = W1[(size_t)k * HID + n];
        const u16 h = f2bf(v);
        w1nh[t3] = h;
        w1nl[t3] = f2bf(v - bf2f(h));
    } else if (tid < 229376) {                // W2 node frags: 8 mt x 8 ks
        const int t4 = tid - 196608;
        const int j = t4 & 7, l = (t4 >> 3) & 63, ks = (t4 >> 9) & 7, mt = t4 >> 12;
        const int n = mt * 16 + (l & 15);
        const int k = ks * 32 + ((l >> 4) << 3) + j;
        const float v = W2[(size_t)k * EMB + n];
        const u16 h = f2bf(v);
        w2nh[t4] = h;
        w2nl[t4] = f2bf(v - bf2f(h));
    }
}

// ---------------------------------------------------------------------------
// Kernel A (MFMA): node MLP. 64 nodes/block, 4 waves. Output z in BF16.
// 2-product split (exact weights) to keep z accurate.
// ---------------------------------------------------------------------------
__global__ __launch_bounds__(256) void node_mfma_kernel(
    const float* __restrict__ x,
    const float* __restrict__ x_mean, const float* __restrict__ x_std,
    const float* __restrict__ b1,
    const float* __restrict__ bn_gamma, const float* __restrict__ bn_beta,
    const float* __restrict__ bn_mean,  const float* __restrict__ bn_var,
    const float* __restrict__ b2,
    const u16* __restrict__ w1nh, const u16* __restrict__ w1nl,
    const u16* __restrict__ w2nh, const u16* __restrict__ w2nl,
    u16* __restrict__ z)
{
    __shared__ __align__(16) u16 XF[8192];    // 16 KB: [slot 0..3][nt 0..3][512]
    __shared__ __align__(16) u16 HF[16384];   // 32 KB: [ks2 0..7][nt 0..3][512]

    const int t   = threadIdx.x;
    const int w   = t >> 6;
    const int l   = t & 63;
    const int l15 = l & 15;
    const int l4  = l >> 4;
    const int n0  = blockIdx.x * 64;
    const int nd  = (n0 + l < N_NODES) ? (n0 + l) : (N_NODES - 1);

    // ---- stage xf: thread (w,l) = node l, channels [w*32, w*32+32) ----
    {
        const float* xp = x + (size_t)nd * IN_CH + w * 32;
        float v[32];
        #pragma unroll
        for (int q = 0; q < 8; ++q)
            *reinterpret_cast<float4*>(&v[q * 4]) = *reinterpret_cast<const float4*>(xp + q * 4);
        #pragma unroll
        for (int q = 0; q < 8; ++q) {
            float4 m4 = *reinterpret_cast<const float4*>(x_mean + w * 32 + q * 4);
            float4 s4 = *reinterpret_cast<const float4*>(x_std  + w * 32 + q * 4);
            float mm[4] = {m4.x, m4.y, m4.z, m4.w};
            float ss[4] = {s4.x, s4.y, s4.z, s4.w};
            #pragma unroll
            for (int e = 0; e < 4; ++e) {
                float val = v[q * 4 + e];
                if (!isfinite(val)) val = 0.0f;
                val = (val - mm[e]) / ss[e];
                v[q * 4 + e] = fminf(fmaxf(val, -10.0f), 10.0f);
            }
        }
        #pragma unroll
        for (int q = 0; q < 4; ++q) {
            const int base = (w * 4 + l4) * 512 + (l15 + 16 * q) * 8;
            store8(XF, base, &v[q * 8]);
        }
    }
    __syncthreads();

    // ---- L1: acc[m][nt], wave owns mt {4w..4w+3}, K=128 ----
    f32x4 acc[4][4];
    #pragma unroll
    for (int m = 0; m < 4; ++m)
        #pragma unroll
        for (int nt = 0; nt < 4; ++nt) acc[m][nt] = (f32x4){0.f, 0.f, 0.f, 0.f};

    #pragma unroll
    for (int sl = 0; sl < 4; ++sl) {
        bf16x8 wh[4], wl[4];
        #pragma unroll
        for (int m = 0; m < 4; ++m) {
            const size_t bo = ((size_t)((w * 4 + m) * 4 + sl) * 64 + l) * 8;
            wh[m] = *reinterpret_cast<const bf16x8*>(&w1nh[bo]);
            wl[m] = *reinterpret_cast<const bf16x8*>(&w1nl[bo]);
        }
        bf16x8 fh[4];
        #pragma unroll
        for (int nt = 0; nt < 4; ++nt)
            fh[nt] = *reinterpret_cast<const bf16x8*>(&XF[(sl * 4 + nt) * 512 + l * 8]);
        __builtin_amdgcn_s_setprio(1);
        #pragma unroll
        for (int m = 0; m < 4; ++m)
            #pragma unroll
            for (int nt = 0; nt < 4; ++nt)
                acc[m][nt] = __builtin_amdgcn_mfma_f32_16x16x32_bf16(wh[m], fh[nt], acc[m][nt], 0, 0, 0);
        #pragma unroll
        for (int m = 0; m < 4; ++m)
            #pragma unroll
            for (int nt = 0; nt < 4; ++nt)
                acc[m][nt] = __builtin_amdgcn_mfma_f32_16x16x32_bf16(wl[m], fh[nt], acc[m][nt], 0, 0, 0);
        __builtin_amdgcn_s_setprio(0);
    }

    // ---- epilogue 1: BN + relu -> HF (bf16) ----
    #pragma unroll
    for (int m = 0; m < 4; ++m) {
        const int mt = w * 4 + m;
        const int nb = mt * 16 + l4 * 4;
        float4 b1v = *reinterpret_cast<const float4*>(b1 + nb);
        float4 gv  = *reinterpret_cast<const float4*>(bn_gamma + nb);
        float4 bev = *reinterpret_cast<const float4*>(bn_beta + nb);
        float4 mev = *reinterpret_cast<const float4*>(bn_mean + nb);
        float4 vav = *reinterpret_cast<const float4*>(bn_var + nb);
        float scale[4], shift[4];
        float bb[4] = {b1v.x, b1v.y, b1v.z, b1v.w};
        float gg[4] = {gv.x, gv.y, gv.z, gv.w};
        float be[4] = {bev.x, bev.y, bev.z, bev.w};
        float me[4] = {mev.x, mev.y, mev.z, mev.w};
        float va[4] = {vav.x, vav.y, vav.z, vav.w};
        #pragma unroll
        for (int r = 0; r < 4; ++r) {
            scale[r] = gg[r] * rsqrtf(va[r] + BN_EPS);
            shift[r] = (bb[r] - me[r]) * scale[r] + be[r];
        }
        #pragma unroll
        for (int nt = 0; nt < 4; ++nt) {
            float v[4];
            #pragma unroll
            for (int r = 0; r < 4; ++r)
                v[r] = fmaxf(fmaf(acc[m][nt][r], scale[r], shift[r]), 0.0f);
            u32x2 hv;
            hv[0] = pk2(v[0], v[1]);
            hv[1] = pk2(v[2], v[3]);
            const int base = ((mt >> 1) * 4 + nt) * 512
                           + (l15 + 16 * ((mt & 1) * 2 + (l4 >> 1))) * 8
                           + (l4 & 1) * 4;
            *reinterpret_cast<u32x2*>(&HF[base]) = hv;
        }
    }
    __syncthreads();

    // ---- L2: acc2[m2][nt], wave owns mt2 {2w, 2w+1}, K=256 ----
    f32x4 acc2[2][4];
    #pragma unroll
    for (int m2 = 0; m2 < 2; ++m2)
        #pragma unroll
        for (int nt = 0; nt < 4; ++nt) acc2[m2][nt] = (f32x4){0.f, 0.f, 0.f, 0.f};

    #pragma unroll
    for (int ks2 = 0; ks2 < 8; ++ks2) {
        bf16x8 wh2[2], wl2[2];
        #pragma unroll
        for (int m2 = 0; m2 < 2; ++m2) {
            const size_t bo = ((size_t)((w * 2 + m2) * 8 + ks2) * 64 + l) * 8;
            wh2[m2] = *reinterpret_cast<const bf16x8*>(&w2nh[bo]);
            wl2[m2] = *reinterpret_cast<const bf16x8*>(&w2nl[bo]);
        }
        bf16x8 fh[4];
        #pragma unroll
        for (int nt = 0; nt < 4; ++nt)
            fh[nt] = *reinterpret_cast<const bf16x8*>(&HF[(ks2 * 4 + nt) * 512 + l * 8]);
        __builtin_amdgcn_s_setprio(1);
        #pragma unroll
        for (int m2 = 0; m2 < 2; ++m2)
            #pragma unroll
            for (int nt = 0; nt < 4; ++nt)
                acc2[m2][nt] = __builtin_amdgcn_mfma_f32_16x16x32_bf16(wh2[m2], fh[nt], acc2[m2][nt], 0, 0, 0);
        #pragma unroll
        for (int m2 = 0; m2 < 2; ++m2)
            #pragma unroll
            for (int nt = 0; nt < 4; ++nt)
                acc2[m2][nt] = __builtin_amdgcn_mfma_f32_16x16x32_bf16(wl2[m2], fh[nt], acc2[m2][nt], 0, 0, 0);
        __builtin_amdgcn_s_setprio(0);
    }

    // ---- epilogue 2: z = bf16(relu(acc2 + b2)) -> global ----
    #pragma unroll
    for (int m2 = 0; m2 < 2; ++m2) {
        const int nb2 = (w * 2 + m2) * 16 + l4 * 4;
        float4 b2v = *reinterpret_cast<const float4*>(b2 + nb2);
        float bb[4] = {b2v.x, b2v.y, b2v.z, b2v.w};
        #pragma unroll
        for (int nt = 0; nt < 4; ++nt) {
            const int node = n0 + nt * 16 + l15;
            if (node < N_NODES) {
                float v0 = fmaxf(acc2[m2][nt][0] + bb[0], 0.0f);
                float v1 = fmaxf(acc2[m2][nt][1] + bb[1], 0.0f);
                float v2 = fmaxf(acc2[m2][nt][2] + bb[2], 0.0f);
                float v3 = fmaxf(acc2[m2][nt][3] + bb[3], 0.0f);
                u32x2 hv;
                hv[0] = pk2(v0, v1);
                hv[1] = pk2(v2, v3);
                *reinterpret_cast<u32x2*>(z + (size_t)node * EMB + nb2) = hv;
            }
        }
    }
}

// ---------------------------------------------------------------------------
// Kernel B (MFMA): 64 pairs/block, 4 waves, r11 schedule, 1-PRODUCT
// (bf16 weights x bf16 features). MFMA floor 79 us.
// ---------------------------------------------------------------------------
__global__ __launch_bounds__(256) void pair_mfma_kernel(
    const u16* __restrict__ z,
    const int* __restrict__ pairs,
    const float* __restrict__ logdeg,
    const u16* __restrict__ w1h,
    const u16* __restrict__ w2h,
    const float* __restrict__ SW1, const float* __restrict__ Sb1,
    const float* __restrict__ Sb2,
    const float* __restrict__ SW3, const float* __restrict__ Sb3,
    float* __restrict__ out)
{
    __shared__ __align__(16) u16 Abuf[8192];   // 16 KB
    __shared__ __align__(16) u16 Bbuf[8192];   // 16 KB
    __shared__ float red[4][4][16];            // 1 KB

    const int t   = threadIdx.x;
    const int w   = t >> 6;        // wave 0..3
    const int l   = t & 63;
    const int l15 = l & 15;
    const int l4  = l >> 4;
    const int p0  = blockIdx.x * PBM;

    // thread (w,l): pair l, channels [w*16, w*16+16) of a 64-ch half.
    const int qb  = (w & 1) * 2;
    const int bS0 = (((w >> 1)) * 4 + l4) * 512 + (l15 + 16 * (qb + 0)) * 8;
    const int bS1 = (((w >> 1)) * 4 + l4) * 512 + (l15 + 16 * (qb + 1)) * 8;
    const int bD0 = ((2 + (w >> 1)) * 4 + l4) * 512 + (l15 + 16 * (qb + 0)) * 8;
    const int bD1 = ((2 + (w >> 1)) * 4 + l4) * 512 + (l15 + 16 * (qb + 1)) * 8;

    const int gp  = (p0 + l < N_PAIRS) ? (p0 + l) : (N_PAIRS - 1);
    const int gsi = pairs[(size_t)gp * 2 + 0];
    const int gdi = pairs[(size_t)gp * 2 + 1];

    // ---- gather both halves (bf16, raw u16x8), stage half-0 -> Abuf ----
    const u16* zs0 = z + (size_t)gsi * EMB + w * 16;
    const u16* zd0 = z + (size_t)gdi * EMB + w * 16;
    u16x8 s00 = *reinterpret_cast<const u16x8*>(zs0);
    u16x8 s01 = *reinterpret_cast<const u16x8*>(zs0 + 8);
    u16x8 d00 = *reinterpret_cast<const u16x8*>(zd0);
    u16x8 d01 = *reinterpret_cast<const u16x8*>(zd0 + 8);
    u16x8 s10 = *reinterpret_cast<const u16x8*>(zs0 + 64);
    u16x8 s11 = *reinterpret_cast<const u16x8*>(zs0 + 72);
    u16x8 d10 = *reinterpret_cast<const u16x8*>(zd0 + 64);
    u16x8 d11 = *reinterpret_cast<const u16x8*>(zd0 + 72);

    *reinterpret_cast<u16x8*>(&Abuf[bS0]) = s00;
    *reinterpret_cast<u16x8*>(&Abuf[bS1]) = s01;
    *reinterpret_cast<u16x8*>(&Abuf[bD0]) = d00;
    *reinterpret_cast<u16x8*>(&Abuf[bD1]) = d01;

    // ---- prefetch epilogue-1 gather data ----
    float ldS[4], ldD[4];
    #pragma unroll
    for (int nt = 0; nt < 4; ++nt) {
        const int pidx = (p0 + nt * 16 + l15 < N_PAIRS) ? (p0 + nt * 16 + l15) : (N_PAIRS - 1);
        ldS[nt] = logdeg[pairs[(size_t)pidx * 2 + 0]];
        ldD[nt] = logdeg[pairs[(size_t)pidx * 2 + 1]];
    }

    __syncthreads();   // bar1

    f32x4 acc[4][4];
    #pragma unroll
    for (int m = 0; m < 4; ++m)
        #pragma unroll
        for (int nt = 0; nt < 4; ++nt) acc[m][nt] = (f32x4){0.f, 0.f, 0.f, 0.f};

    // one 128-K segment; weight register dbuf across sl; 1-product
    auto run_pass = [&](const u16* buf, int k0, int k1, int k2, int k3) {
        const int ksg[4] = {k0, k1, k2, k3};
        bf16x8 wh[2][4];
        #pragma unroll
        for (int m = 0; m < 4; ++m) {
            const size_t bo = ((size_t)((w * 4 + m) * 16 + ksg[0]) * 64 + l) * 8;
            wh[0][m] = *reinterpret_cast<const bf16x8*>(&w1h[bo]);
        }
        #pragma unroll
        for (int sl = 0; sl < 4; ++sl) {
            const int cur = sl & 1;
            if (sl < 3) {
                #pragma unroll
                for (int m = 0; m < 4; ++m) {
                    const size_t bo = ((size_t)((w * 4 + m) * 16 + ksg[sl + 1]) * 64 + l) * 8;
                    wh[cur ^ 1][m] = *reinterpret_cast<const bf16x8*>(&w1h[bo]);
                }
            }
            #pragma unroll
            for (int nh = 0; nh < 2; ++nh) {
                bf16x8 fh[2];
                #pragma unroll
                for (int e = 0; e < 2; ++e)
                    fh[e] = *reinterpret_cast<const bf16x8*>(&buf[(sl * 4 + nh * 2 + e) * 512 + l * 8]);
                __builtin_amdgcn_s_setprio(1);
                #pragma unroll
                for (int m = 0; m < 4; ++m)
                    #pragma unroll
                    for (int e = 0; e < 2; ++e)
                        acc[m][nh * 2 + e] = __builtin_amdgcn_mfma_f32_16x16x32_bf16(wh[cur][m], fh[e], acc[m][nh * 2 + e], 0, 0, 0);
                __builtin_amdgcn_s_setprio(0);
            }
        }
    };

    // rebuild p = s~*d~, ad = |s~-d~| from HELD registers (z already bf16)
    auto rebuildR = [&](u16x8 sa, u16x8 sb, u16x8 da, u16x8 db, float* pv, float* av) {
        #pragma unroll
        for (int qq = 0; qq < 8; ++qq) {
            const float s = bf2f(sa[qq]);
            const float d = bf2f(da[qq]);
            pv[qq] = s * d;
            av[qq] = fabsf(s - d);
        }
        #pragma unroll
        for (int qq = 0; qq < 8; ++qq) {
            const float s = bf2f(sb[qq]);
            const float d = bf2f(db[qq]);
            pv[8 + qq] = s * d;
            av[8 + qq] = fabsf(s - d);
        }
    };

    // ---- seg0 compute + rebuild(half-0 regs) -> Bbuf ----
    run_pass(Abuf, 0, 1, 4, 5);
    {
        float pv[16], av[16];
        rebuildR(s00, s01, d00, d01, pv, av);
        store8(Bbuf, bS0, pv + 0);
        store8(Bbuf, bS1, pv + 8);
        store8(Bbuf, bD0, av + 0);
        store8(Bbuf, bD1, av + 8);
    }
    __syncthreads();   // bar2: Bbuf visible; all Abuf reads retired

    // ---- write held half-1 -> Abuf, compute seg2 from Bbuf ----
    *reinterpret_cast<u16x8*>(&Abuf[bS0]) = s10;
    *reinterpret_cast<u16x8*>(&Abuf[bS1]) = s11;
    *reinterpret_cast<u16x8*>(&Abuf[bD0]) = d10;
    *reinterpret_cast<u16x8*>(&Abuf[bD1]) = d11;
    run_pass(Bbuf, 8, 9, 12, 13);
    __syncthreads();   // bar3

    // ---- seg1 compute + rebuild(half-1 regs) -> Bbuf ----
    run_pass(Abuf, 2, 3, 6, 7);
    {
        float pv[16], av[16];
        rebuildR(s10, s11, d10, d11, pv, av);
        store8(Bbuf, bS0, pv + 0);
        store8(Bbuf, bS1, pv + 8);
        store8(Bbuf, bD0, av + 0);
        store8(Bbuf, bD1, av + 8);
    }
    __syncthreads();   // bar4

    // ---- seg3 compute ----
    run_pass(Bbuf, 10, 11, 14, 15);

    // ---- layer 2 ----
    f32x4 acc2[2][4];
    #pragma unroll
    for (int m2 = 0; m2 < 2; ++m2)
        #pragma unroll
        for (int nt = 0; nt < 4; ++nt) acc2[m2][nt] = (f32x4){0.f, 0.f, 0.f, 0.f};

    auto epi1 = [&](u16* buf, int g) {
        #pragma unroll
        for (int mm = 0; mm < 2; ++mm) {
            const int m  = 2 * g + mm;
            const int mt = w * 4 + m;
            const int nb = mt * 16 + l4 * 4;
            float sb[4], wa[4], wb[4];
            *reinterpret_cast<float4*>(sb) = *reinterpret_cast<const float4*>(&Sb1[nb]);
            *reinterpret_cast<float4*>(wa) = *reinterpret_cast<const float4*>(&SW1[(size_t)512 * HID + nb]);
            *reinterpret_cast<float4*>(wb) = *reinterpret_cast<const float4*>(&SW1[(size_t)513 * HID + nb]);
            #pragma unroll
            for (int nt = 0; nt < 4; ++nt) {
                float v[4];
                #pragma unroll
                for (int r = 0; r < 4; ++r) {
                    float x0 = acc[m][nt][r] + sb[r];
                    x0 = fmaf(ldS[nt], wa[r], x0);
                    x0 = fmaf(ldD[nt], wb[r], x0);
                    v[r] = fmaxf(x0, 0.0f);
                }
                u32x2 hv;
                hv[0] = pk2(v[0], v[1]);
                hv[1] = pk2(v[2], v[3]);
                const int base = (w * 4 + nt) * 512
                               + (l15 + 16 * ((m & 1) * 2 + (l4 >> 1))) * 8
                               + (l4 & 1) * 4;
                *reinterpret_cast<u32x2*>(&buf[base]) = hv;
            }
        }
    };

    auto mfma2 = [&](const u16* buf, int g) {
        #pragma unroll
        for (int cs = 0; cs < 4; ++cs) {
            const int ks2 = cs * 2 + g;
            bf16x8 wh2[2];
            #pragma unroll
            for (int m2 = 0; m2 < 2; ++m2) {
                const size_t bo = ((size_t)((w * 2 + m2) * 8 + ks2) * 64 + l) * 8;
                wh2[m2] = *reinterpret_cast<const bf16x8*>(&w2h[bo]);
            }
            #pragma unroll
            for (int nh = 0; nh < 2; ++nh) {
                bf16x8 fh[2];
                #pragma unroll
                for (int e = 0; e < 2; ++e)
                    fh[e] = *reinterpret_cast<const bf16x8*>(&buf[(cs * 4 + nh * 2 + e) * 512 + l * 8]);
                __builtin_amdgcn_s_setprio(1);
                #pragma unroll
                for (int m2 = 0; m2 < 2; ++m2)
                    #pragma unroll
                    for (int e = 0; e < 2; ++e)
                        acc2[m2][nh * 2 + e] = __builtin_amdgcn_mfma_f32_16x16x32_bf16(wh2[m2], fh[e], acc2[m2][nh * 2 + e], 0, 0, 0);
                __builtin_amdgcn_s_setprio(0);
            }
        }
    };

    epi1(Abuf, 0);
    __syncthreads();         // bar5
    epi1(Bbuf, 1);           // overlaps mfma2(A)
    mfma2(Abuf, 0);
    __syncthreads();         // bar6
    mfma2(Bbuf, 1);

    // ---- epilogue 2 + layer 3 ----
    {
        float part[4] = {0.f, 0.f, 0.f, 0.f};
        #pragma unroll
        for (int m2 = 0; m2 < 2; ++m2) {
            const int nb2 = (w * 2 + m2) * 16 + l4 * 4;
            float sb[4], w3[4];
            *reinterpret_cast<float4*>(sb) = *reinterpret_cast<const float4*>(&Sb2[nb2]);
            *reinterpret_cast<float4*>(w3) = *reinterpret_cast<const float4*>(&SW3[nb2]);
            #pragma unroll
            for (int nt = 0; nt < 4; ++nt)
                #pragma unroll
                for (int r = 0; r < 4; ++r)
                    part[nt] = fmaf(fmaxf(acc2[m2][nt][r] + sb[r], 0.0f), w3[r], part[nt]);
        }
        #pragma unroll
        for (int nt = 0; nt < 4; ++nt) {
            part[nt] += __shfl_xor(part[nt], 16);
            part[nt] += __shfl_xor(part[nt], 32);
        }
        if (l < 16) {
            #pragma unroll
            for (int nt = 0; nt < 4; ++nt) red[w][nt][l15] = part[nt];
        }
    }
    __syncthreads();   // bar7

    if (t < 64) {
        const int nt = t >> 4, pp = t & 15;
        float v = red[0][nt][pp] + red[1][nt][pp] + red[2][nt][pp] + red[3][nt][pp] + Sb3[0];
        if (isnan(v)) v = 0.0f;
        else if (isinf(v)) v = (v > 0.0f) ? 20.0f : -20.0f;
        const int pidx = p0 + nt * 16 + pp;
        if (pidx < N_PAIRS) out[pidx] = v;
    }
}

// ---------------------------------------------------------------------------
extern "C" void kernel_launch(void* const* d_in, const int* in_sizes, int n_in,
                              void* d_out, int out_size, void* d_ws, size_t ws_size,
                              hipStream_t stream)
{
    const float* x        = (const float*)d_in[0];
    // d_in[1] = edge_index : unused by the reference
    const int*   pairs    = (const int*)d_in[2];
    const float* x_mean   = (const float*)d_in[3];
    const float* x_std    = (const float*)d_in[4];
    const float* logdeg   = (const float*)d_in[5];
    const float* W1       = (const float*)d_in[6];
    const float* b1       = (const float*)d_in[7];
    const float* bn_gamma = (const float*)d_in[8];
    const float* bn_beta  = (const float*)d_in[9];
    const float* bn_mean  = (const float*)d_in[10];
    const float* bn_var   = (const float*)d_in[11];
    const float* W2       = (const float*)d_in[12];
    const float* b2       = (const float*)d_in[13];
    const float* SW1      = (const float*)d_in[14];
    const float* Sb1      = (const float*)d_in[15];
    const float* SW2      = (const float*)d_in[16];
    const float* Sb2      = (const float*)d_in[17];
    const float* SW3      = (const float*)d_in[18];
    const float* Sb3      = (const float*)d_in[19];

    float* outp = (float*)d_out;

    // ws layout (z bf16: 25,600,000 B)
    char* wsb = (char*)d_ws;
    u16* zbuf = (u16*)wsb;
    u16* w1h  = (u16*)(wsb + 25600000);                 // 262144 B
    u16* w2h  = (u16*)(wsb + 25862144);                 // 65536 B
    u16* w1nh = (u16*)(wsb + 25927680);                 // 65536 B
    u16* w1nl = (u16*)(wsb + 25993216);                 // 65536 B
    u16* w2nh = (u16*)(wsb + 26058752);                 // 65536 B
    u16* w2nl = (u16*)(wsb + 26124288);                 // 65536 B (end 26,189,824)

    prep_weights<<<896, 256, 0, stream>>>(SW1, SW2, W1, W2,
                                          w1h, w2h,
                                          w1nh, w1nl, w2nh, w2nl);

    node_mfma_kernel<<<(N_NODES + 63) / 64, 256, 0, stream>>>(
        x, x_mean, x_std, b1, bn_gamma, bn_beta, bn_mean, bn_var, b2,
        w1nh, w1nl, w2nh, w2nl, zbuf);

    pair_mfma_kernel<<<(N_PAIRS + PBM - 1) / PBM, 256, 0, stream>>>(
        zbuf, pairs, logdeg, w1h, w2h, SW1, Sb1, Sb2, SW3, Sb3, outp);
}